// Round 12
// baseline (418.400 us; speedup 1.0000x reference)
//
#include <hip/hip_runtime.h>
#include <hip/hip_bf16.h>
#include <stdint.h>

typedef __attribute__((ext_vector_type(8)))  short s16x8;
typedef __attribute__((ext_vector_type(4)))  short s16x4;
typedef __attribute__((ext_vector_type(4)))  float f32x4;
typedef __attribute__((ext_vector_type(16))) float f32x16;
typedef __attribute__((ext_vector_type(4)))  int   s32x4;

#define DEV static __device__ __forceinline__

DEV ushort f2bu(float f){
  unsigned u = __builtin_bit_cast(unsigned, f);
  return (ushort)((u + 0x7fffu + ((u >> 16) & 1u)) >> 16);   // RNE f32->bf16
}
DEV ushort f2bn(float f){
  return __builtin_bit_cast(ushort, __float2bfloat16(f));
}
DEV unsigned cvtpk(float lo, float hi){
  unsigned d;
  asm("v_cvt_pk_bf16_f32 %0, %1, %2" : "=v"(d) : "v"(lo), "v"(hi));
  return d;
}

DEV void gload16(const void* g, void* l){
  __builtin_amdgcn_global_load_lds((const __attribute__((address_space(1))) void*)g,
                                   (__attribute__((address_space(3))) void*)l, 16, 0, 0);
}

#define SCALE_C 0.18033688f   // 0.125 * log2(e), folded into Q projections

// ---------------- fused f32->bf16 conversions + f32 bias concat ----------------
struct ConvArgs {
  const float* src[17];
  void*        dst[17];
  int blk_end[17];
  int nel[17];
  unsigned f32mask;
};

__global__ void __launch_bounds__(256) k_conv(ConvArgs a){
  int bi = blockIdx.x, seg = 0;
  while (bi >= a.blk_end[seg]) seg++;
  int b0 = seg ? a.blk_end[seg-1] : 0;
  long off = (long)(bi - b0)*2048 + (long)threadIdx.x*8;
  if (off >= a.nel[seg]) return;
  const float* s = a.src[seg] + off;
  f32x4 v0 = *(const f32x4*)s;
  f32x4 v1 = *(const f32x4*)(s+4);
  if ((a.f32mask >> seg) & 1u){
    float* d = (float*)a.dst[seg] + off;
    *(f32x4*)d = v0; *(f32x4*)(d+4) = v1;
  } else {
    ushort* d = (ushort*)a.dst[seg] + off;
    s16x8 o;
#pragma unroll
    for (int j = 0; j < 4; j++){ o[j] = (short)f2bu(v0[j]); o[4+j] = (short)f2bu(v1[j]); }
    *(s16x8*)d = o;
  }
}

// ---------------- 128x128 dbuf GEMM, bf16 out with scale (cross-Q) ----------------
__global__ void __launch_bounds__(256) k_gemm(const ushort* __restrict__ A, const ushort* __restrict__ W,
    const float* __restrict__ bias, ushort* __restrict__ Cb,
    int M, int N, int K, int lda, int ldb, float scale)
{
  __shared__ __align__(16) ushort lsA[2][128*64];
  __shared__ __align__(16) ushort lsB[2][128*64];
  const int t = threadIdx.x, w = t >> 6, u = t & 63, lr = u & 15, lk = u >> 4;
  const int m0 = blockIdx.y * 128, n0 = blockIdx.x * 128;
  const int wm = w >> 1, wn = w & 1;
  const int rA = t >> 3, c8 = (t & 7) * 8;
  const ushort* Ap = A + (size_t)(m0 + rA) * lda + c8;
  const ushort* Wp = W + (size_t)(n0 + rA) * ldb + c8;
  f32x4 acc[4][4] = {};
  const int nk = K >> 6;

  auto stage = [&](int k0, int buf){
#pragma unroll
    for (int j = 0; j < 4; j++){
      gload16(Ap + (size_t)j*32*lda + k0, &lsA[buf][0] + j*2048 + w*512);
      gload16(Wp + (size_t)j*32*ldb + k0, &lsB[buf][0] + j*2048 + w*512);
    }
  };
  stage(0, 0);
  for (int tk = 0; tk < nk; ++tk){
    __syncthreads();
    if (tk + 1 < nk) stage((tk + 1) << 6, (tk + 1) & 1);
    const ushort* La = &lsA[tk & 1][0];
    const ushort* Lb = &lsB[tk & 1][0];
#pragma unroll
    for (int ks = 0; ks < 2; ks++){
      s16x8 af[4], bfr[4];
#pragma unroll
      for (int i = 0; i < 4; i++) af[i]  = *(const s16x8*)(La + (wm*64 + i*16 + lr)*64 + ks*32 + lk*8);
#pragma unroll
      for (int i = 0; i < 4; i++) bfr[i] = *(const s16x8*)(Lb + (wn*64 + i*16 + lr)*64 + ks*32 + lk*8);
#pragma unroll
      for (int mi = 0; mi < 4; mi++)
#pragma unroll
        for (int ni = 0; ni < 4; ni++)
          acc[mi][ni] = __builtin_amdgcn_mfma_f32_16x16x32_bf16(af[mi], bfr[ni], acc[mi][ni], 0, 0, 0);
    }
  }

#pragma unroll
  for (int mi = 0; mi < 4; mi++){
#pragma unroll
    for (int ni = 0; ni < 4; ni++){
      const int row = m0 + wm*64 + mi*16 + lk*4;
      const int col = n0 + wn*64 + ni*16 + lr;
      const float bv = bias[col];
#pragma unroll
      for (int i = 0; i < 4; i++){
        float v = (acc[mi][ni][i] + bv) * scale;
        Cb[(size_t)(row + i) * N + col] = f2bn(v);
      }
    }
  }
}

// ---------------- 128x128 dbuf GEMM, split-K f32 out (wo1/wo2/FFN2) ----------------
__global__ void __launch_bounds__(256) k_gemmS(const ushort* __restrict__ A, const ushort* __restrict__ W,
    const float* __restrict__ bias, float* __restrict__ Cf,
    int M, int N, int Kext, int lda, int ldb, long long sstride)
{
  __shared__ __align__(16) ushort lsA[2][128*64];
  __shared__ __align__(16) ushort lsB[2][128*64];
  const int t = threadIdx.x, w = t >> 6, u = t & 63, lr = u & 15, lk = u >> 4;
  const int m0 = blockIdx.y * 128, n0 = blockIdx.x * 128;
  const int s = blockIdx.z;
  const int wm = w >> 1, wn = w & 1;
  const int rA = t >> 3, c8 = (t & 7) * 8;
  const ushort* Ap = A + (size_t)(m0 + rA) * lda + (size_t)s * Kext + c8;
  const ushort* Wp = W + (size_t)(n0 + rA) * ldb + (size_t)s * Kext + c8;
  if (s){ bias = nullptr; Cf += sstride; }
  f32x4 acc[4][4] = {};
  const int nk = Kext >> 6;

  auto stage = [&](int k0, int buf){
#pragma unroll
    for (int j = 0; j < 4; j++){
      gload16(Ap + (size_t)j*32*lda + k0, &lsA[buf][0] + j*2048 + w*512);
      gload16(Wp + (size_t)j*32*ldb + k0, &lsB[buf][0] + j*2048 + w*512);
    }
  };
  stage(0, 0);
  for (int tk = 0; tk < nk; ++tk){
    __syncthreads();
    if (tk + 1 < nk) stage((tk + 1) << 6, (tk + 1) & 1);
    const ushort* La = &lsA[tk & 1][0];
    const ushort* Lb = &lsB[tk & 1][0];
#pragma unroll
    for (int ks = 0; ks < 2; ks++){
      s16x8 af[4], bfr[4];
#pragma unroll
      for (int i = 0; i < 4; i++) af[i]  = *(const s16x8*)(La + (wm*64 + i*16 + lr)*64 + ks*32 + lk*8);
#pragma unroll
      for (int i = 0; i < 4; i++) bfr[i] = *(const s16x8*)(Lb + (wn*64 + i*16 + lr)*64 + ks*32 + lk*8);
#pragma unroll
      for (int mi = 0; mi < 4; mi++)
#pragma unroll
        for (int ni = 0; ni < 4; ni++)
          acc[mi][ni] = __builtin_amdgcn_mfma_f32_16x16x32_bf16(af[mi], bfr[ni], acc[mi][ni], 0, 0, 0);
    }
  }

#pragma unroll
  for (int mi = 0; mi < 4; mi++){
#pragma unroll
    for (int ni = 0; ni < 4; ni++){
      const int row = m0 + wm*64 + mi*16 + lk*4;
      const int col = n0 + wn*64 + ni*16 + lr;
      const float bv = bias ? bias[col] : 0.f;
#pragma unroll
      for (int i = 0; i < 4; i++)
        Cf[(size_t)(row + i) * N + col] = acc[mi][ni][i] + bv;
    }
  }
}

// ---------------- 256x256 8-phase GEMM (T2+T3+T4+T5) ----------------
// MODE 0: bf16 out, cols<scaleLim scaled; MODE 2: relu + bf16 out.
template<int MODE>
__global__ void __launch_bounds__(512, 1) k_gemm256(const ushort* __restrict__ A, const ushort* __restrict__ W,
    const float* __restrict__ bias, ushort* __restrict__ Cb,
    int N, int Ktot, int lda, int ldb, int scaleLim, float scale)
{
  __shared__ __align__(16) ushort lsA[2][256*64];
  __shared__ __align__(16) ushort lsB[2][256*64];
  const int t = threadIdx.x, w = t >> 6, u = t & 63, lr = u & 15, lk = u >> 4;
  const int gx = gridDim.x;
  const int nwg = gx * gridDim.y;
  const int id = blockIdx.y * gx + blockIdx.x;
  const int swz = (id & 7) * (nwg >> 3) + (id >> 3);      // bijective: nwg % 8 == 0
  const int n0 = (swz % gx) * 256, m0 = (swz / gx) * 256;
  const int wm = w >> 2, wn = w & 3;
  const int nt = Ktot >> 6;

  const int r0 = w*8 + (u >> 3), cc = u & 7;
  const int csw = 8 * (cc ^ (r0 & 7));
  const ushort* Ap = A + (size_t)(m0 + r0) * lda + csw;
  const ushort* Wp = W + (size_t)(n0 + r0) * ldb + csw;

  f32x4 acc[8][4] = {};
  const int swl = lr & 7;
  s16x8 afr[4], bfr[4];

#pragma unroll
  for (int j = 0; j < 4; j++){
    gload16(Ap + (size_t)(64*j)*lda, &lsA[0][0] + w*512 + j*4096);
    gload16(Wp + (size_t)(64*j)*ldb, &lsB[0][0] + w*512 + j*4096);
  }
  asm volatile("s_waitcnt vmcnt(0)" ::: "memory");
  __builtin_amdgcn_s_barrier();

  for (int tk = 0; tk < nt; ++tk){
    const char* La = (const char*)&lsA[tk & 1][0];
    const char* Lb = (const char*)&lsB[tk & 1][0];
    ushort* dA = &lsA[(tk & 1) ^ 1][0] + w*512;
    ushort* dB = &lsB[(tk & 1) ^ 1][0] + w*512;
    const bool pf = (tk + 1 < nt);
    const size_t k1 = (size_t)(tk + 1) << 6;

    // ---- phase 1 ----
#pragma unroll
    for (int i = 0; i < 4; i++)
      afr[i] = *(const s16x8*)(La + (wm*128 + i*16 + lr)*128 + ((lk ^ swl) * 16));
#pragma unroll
    for (int i = 0; i < 4; i++)
      bfr[i] = *(const s16x8*)(Lb + (wn*64 + i*16 + lr)*128 + ((lk ^ swl) * 16));
    if (pf){
      gload16(Ap + k1, dA);
      gload16(Wp + k1, dB);
      gload16(Ap + (size_t)64*lda + k1, dA + 4096);
      gload16(Wp + (size_t)64*ldb + k1, dB + 4096);
    }
    __builtin_amdgcn_s_barrier();
    asm volatile("s_waitcnt lgkmcnt(0)" ::: "memory");
    __builtin_amdgcn_s_setprio(1);
#pragma unroll
    for (int mi = 0; mi < 4; mi++)
#pragma unroll
      for (int ni = 0; ni < 4; ni++)
        acc[mi][ni] = __builtin_amdgcn_mfma_f32_16x16x32_bf16(afr[mi], bfr[ni], acc[mi][ni], 0, 0, 0);
    __builtin_amdgcn_s_setprio(0);
    __builtin_amdgcn_s_barrier();

    // ---- phase 2 ----
#pragma unroll
    for (int i = 0; i < 4; i++)
      afr[i] = *(const s16x8*)(La + (wm*128 + 64 + i*16 + lr)*128 + ((lk ^ swl) * 16));
    if (pf){
      gload16(Ap + (size_t)128*lda + k1, dA + 8192);
      gload16(Wp + (size_t)128*ldb + k1, dB + 8192);
      gload16(Ap + (size_t)192*lda + k1, dA + 12288);
      gload16(Wp + (size_t)192*ldb + k1, dB + 12288);
    }
    __builtin_amdgcn_s_barrier();
    asm volatile("s_waitcnt lgkmcnt(0)" ::: "memory");
    __builtin_amdgcn_s_setprio(1);
#pragma unroll
    for (int mi = 0; mi < 4; mi++)
#pragma unroll
      for (int ni = 0; ni < 4; ni++)
        acc[4+mi][ni] = __builtin_amdgcn_mfma_f32_16x16x32_bf16(afr[mi], bfr[ni], acc[4+mi][ni], 0, 0, 0);
    __builtin_amdgcn_s_setprio(0);
    __builtin_amdgcn_s_barrier();

    // ---- phase 3 ----
#pragma unroll
    for (int i = 0; i < 4; i++)
      afr[i] = *(const s16x8*)(La + (wm*128 + i*16 + lr)*128 + (((4 + lk) ^ swl) * 16));
#pragma unroll
    for (int i = 0; i < 4; i++)
      bfr[i] = *(const s16x8*)(Lb + (wn*64 + i*16 + lr)*128 + (((4 + lk) ^ swl) * 16));
    __builtin_amdgcn_s_barrier();
    asm volatile("s_waitcnt lgkmcnt(0)" ::: "memory");
    __builtin_amdgcn_s_setprio(1);
#pragma unroll
    for (int mi = 0; mi < 4; mi++)
#pragma unroll
      for (int ni = 0; ni < 4; ni++)
        acc[mi][ni] = __builtin_amdgcn_mfma_f32_16x16x32_bf16(afr[mi], bfr[ni], acc[mi][ni], 0, 0, 0);
    __builtin_amdgcn_s_setprio(0);
    __builtin_amdgcn_s_barrier();

    // ---- phase 4 ----
#pragma unroll
    for (int i = 0; i < 4; i++)
      afr[i] = *(const s16x8*)(La + (wm*128 + 64 + i*16 + lr)*128 + (((4 + lk) ^ swl) * 16));
    __builtin_amdgcn_s_barrier();
    asm volatile("s_waitcnt lgkmcnt(0)" ::: "memory");
    __builtin_amdgcn_s_setprio(1);
#pragma unroll
    for (int mi = 0; mi < 4; mi++)
#pragma unroll
      for (int ni = 0; ni < 4; ni++)
        acc[4+mi][ni] = __builtin_amdgcn_mfma_f32_16x16x32_bf16(afr[mi], bfr[ni], acc[4+mi][ni], 0, 0, 0);
    __builtin_amdgcn_s_setprio(0);
    asm volatile("s_waitcnt vmcnt(0)" ::: "memory");
    __builtin_amdgcn_s_barrier();
  }

#pragma unroll
  for (int mi = 0; mi < 8; mi++){
#pragma unroll
    for (int ni = 0; ni < 4; ni++){
      const int row = m0 + wm*128 + mi*16 + lk*4;
      const int col = n0 + wn*64 + ni*16 + lr;
      const float bv = bias[col];
#pragma unroll
      for (int i = 0; i < 4; i++){
        float v = acc[mi][ni][i] + bv;
        if (MODE == 2) v = fmaxf(v, 0.f);
        if (MODE == 0 && col < scaleLim) v *= scale;
        Cb[(size_t)(row + i) * N + col] = f2bn(v);
      }
    }
  }
}

// ---------------- V transpose: [B,S,(stride)] head-block -> Vt[B,H,64,S] ----------------
__global__ void __launch_bounds__(256) k_vt(const ushort* __restrict__ V, ushort* __restrict__ Vt,
                                            int stride, int S)
{
  __shared__ ushort tile[64][72];
  const int st = blockIdx.x*64, h = blockIdx.y, b = blockIdx.z;
  const int r = threadIdx.x >> 3, c8 = (threadIdx.x & 7)*8;
#pragma unroll
  for (int j = 0; j < 2; j++){
    int s = r + j*32;
    s16x8 v = *(const s16x8*)(V + (size_t)(b*S + st + s)*stride + h*64 + c8);
    *(s16x8*)&tile[s][c8] = v;
  }
  __syncthreads();
#pragma unroll
  for (int j = 0; j < 2; j++){
    int d = r + j*32;
    s16x8 o;
#pragma unroll
    for (int e = 0; e < 8; e++) o[e] = tile[c8+e][d];
    *(s16x8*)(Vt + ((size_t)((b*16 + h)*64 + d))*S + st + c8) = o;
  }
}

// ---------------- flash attention: 4 waves, 32x32 MFMA, in-register P ----------------
// Q pre-scaled by 0.125*log2(e); m=0 softmax (exp2 direct). QBLK=128 (32 q/wave), KVBLK=64.
// S^T via mfma_32x32x16(K,Q): lane holds P[q=lane&31][16 keys]; cvt_pk + shfl_xor(32)
// rebuilds the PV A-fragment in-register -> zero P LDS traffic.
// CAUSAL: grid (32, 8): q-tiles {15-y, y}. cross: grid (32, 16).
template<bool CAUSAL>
__global__ void __launch_bounds__(256) k_attn(const ushort* __restrict__ Q, const ushort* __restrict__ Kg,
    const ushort* __restrict__ Vt, ushort* __restrict__ O, int sQ, int sK, int SQ, int SKV)
{
  __shared__ __align__(16) ushort Kl[2][64*64];   // [key][d], swizzled
  __shared__ __align__(16) ushort Vl[2][64*64];   // [d][key], swizzled
  const int t = threadIdx.x, l = t & 63, wq = t >> 6;
  const int hi = l >> 5, q32 = l & 31;
  const int hb = blockIdx.x;
  const int b = hb >> 4, h = hb & 15;
  const int srow = t >> 3, scol = t & 7;
  const size_t kvbase = (size_t)b * SKV;
  const size_t vtbase = (size_t)((b*16 + h)*64);

  auto stage = [&](int kt, int buf){
#pragma unroll
    for (int p = 0; p < 2; p++){
      int row = srow + p*32;
      gload16(Kg + (kvbase + kt*64 + row)*sK + h*64 + 8*(scol ^ (row & 7)),
              &Kl[buf][0] + p*2048 + t*8);
      gload16(Vt + (vtbase + row)*SKV + kt*64 + 8*(scol ^ (row & 7)),
              &Vl[buf][0] + p*2048 + t*8);
    }
  };

  const int NREP = CAUSAL ? 2 : 1;
#pragma unroll 1
  for (int rep = 0; rep < NREP; rep++){
    const int qt = CAUSAL ? (rep ? (int)blockIdx.y : (int)(2*gridDim.y - 1 - blockIdx.y))
                          : (int)blockIdx.y;
    const int q0 = qt * 128;
    const int qg = q0 + wq*32 + q32;          // this lane's q (as S^T column)

    // Q B-fragment: lane holds Q[q=qg][d = step*16 + hi*8 + j]
    const ushort* qp = Q + (size_t)(b*SQ + qg) * sQ + h*64 + hi*8;
    s16x8 qf[4];
#pragma unroll
    for (int st2 = 0; st2 < 4; st2++) qf[st2] = *(const s16x8*)(qp + st2*16);

    f32x16 oacc[2] = {};
    float lsum = 0.f;
    const int nkt = CAUSAL ? (2*qt + 2) : (SKV >> 6);

    stage(0, 0);
    __syncthreads();

#pragma unroll 1
    for (int kt = 0; kt < nkt; kt++){
      const int buf = kt & 1;
      if (kt + 1 < nkt) stage(kt + 1, buf ^ 1);
      const char* Kc = (const char*)&Kl[buf][0];
      const char* Vc = (const char*)&Vl[buf][0];

      // S^T: sacc[mg] covers keys 32mg..32mg+31 for q=q32 (col)
      f32x16 sacc[2] = {};
      __builtin_amdgcn_s_setprio(1);
#pragma unroll
      for (int mg = 0; mg < 2; mg++){
        const int krow = 32*mg + q32;
#pragma unroll
        for (int st2 = 0; st2 < 4; st2++){
          s16x8 kf = *(const s16x8*)(Kc + krow*128 + (((st2*2 + hi) ^ (krow & 7)) * 16));
          sacc[mg] = __builtin_amdgcn_mfma_f32_32x32x16_bf16(kf, qf[st2], sacc[mg], 0, 0, 0);
        }
      }
      __builtin_amdgcn_s_setprio(0);

      if (CAUSAL && kt >= 2*qt){
#pragma unroll
        for (int mg = 0; mg < 2; mg++)
#pragma unroll
          for (int r = 0; r < 16; r++){
            int key = kt*64 + 32*mg + (r & 3) + 8*(r >> 2) + 4*hi;
            if (key > qg) sacc[mg][r] = -1e30f;
          }
      }

      // exp2 + row-sum (per-lane, q = q32; partner lane holds the other 16 keys)
#pragma unroll
      for (int mg = 0; mg < 2; mg++)
#pragma unroll
        for (int r = 0; r < 16; r++){
          float p = __builtin_exp2f(sacc[mg][r]);
          sacc[mg][r] = p; lsum += p;
        }

      // PV: per mg, pack to bf16 dwords, cross-half exchange, 2 key-steps x 2 d-halves
      __builtin_amdgcn_s_setprio(1);
#pragma unroll
      for (int mg = 0; mg < 2; mg++){
        unsigned dw[8];
#pragma unroll
        for (int j = 0; j < 8; j++) dw[j] = cvtpk(sacc[mg][2*j], sacc[mg][2*j+1]);
#pragma unroll
        for (int ks = 0; ks < 2; ks++){
          unsigned j0 = dw[ks*4+0], j1 = dw[ks*4+1], j2 = dw[ks*4+2], j3 = dw[ks*4+3];
          unsigned x0 = __shfl_xor(j0, 32), x1 = __shfl_xor(j1, 32);
          unsigned x2 = __shfl_xor(j2, 32), x3 = __shfl_xor(j3, 32);
          s32x4 av;
          av[0] = (int)(hi ? x2 : j0);
          av[1] = (int)(hi ? x3 : j1);
          av[2] = (int)(hi ? j2 : x0);
          av[3] = (int)(hi ? j3 : x1);
          s16x8 af = __builtin_bit_cast(s16x8, av);
          const int kchunk = mg*4 + ks*2 + hi;          // 8-key chunk index in Vt row
#pragma unroll
          for (int dh = 0; dh < 2; dh++){
            const int drow = q32 + 32*dh;
            s16x8 vf = *(const s16x8*)(Vc + drow*128 + ((kchunk ^ (drow & 7)) * 16));
            oacc[dh] = __builtin_amdgcn_mfma_f32_32x32x16_bf16(af, vf, oacc[dh], 0, 0, 0);
          }
        }
      }
      __builtin_amdgcn_s_setprio(0);
      __syncthreads();
    }

    // normalize: lane holds lsum for q=q32 over its 32 keys/tile; partner adds the rest
    lsum += __shfl_xor(lsum, 32);
    float il = 1.f / lsum;
    float invl[16];
#pragma unroll
    for (int r = 0; r < 16; r++)
      invl[r] = __shfl(il, (r & 3) + 8*(r >> 2) + 4*hi);

#pragma unroll
    for (int dh = 0; dh < 2; dh++)
#pragma unroll
      for (int r = 0; r < 16; r++){
        int qrow = q0 + wq*32 + (r & 3) + 8*(r >> 2) + 4*hi;
        O[(size_t)(b*SQ + qrow)*1024 + h*64 + q32 + 32*dh] = f2bn(oacc[dh][r] * invl[r]);
      }
  }
}

// ---------------- residual + LayerNorm (E=1024), optional second partial ----------------
template<bool WB16>
__global__ void __launch_bounds__(256) k_ln(const float* __restrict__ R, const float* __restrict__ P,
    const float* __restrict__ P2, const float* __restrict__ G, const float* __restrict__ Bv,
    float* __restrict__ Of, ushort* __restrict__ Ob)
{
  const int row = blockIdx.x, t = threadIdx.x, w = t >> 6, u = t & 63;
  const size_t base = (size_t)row * 1024 + t * 4;
  f32x4 r = *(const f32x4*)(R + base);
  f32x4 p = *(const f32x4*)(P + base);
  f32x4 v = r + p;
  if (P2){ f32x4 p2 = *(const f32x4*)(P2 + base); v += p2; }
  float s = 0.f, q = 0.f;
#pragma unroll
  for (int j = 0; j < 4; j++){ s += v[j]; q += v[j]*v[j]; }
#pragma unroll
  for (int md = 1; md < 64; md <<= 1){ s += __shfl_xor(s, md); q += __shfl_xor(q, md); }
  __shared__ float ps[4], pq[4];
  if (u == 0){ ps[w] = s; pq[w] = q; }
  __syncthreads();
  s = ps[0] + ps[1] + ps[2] + ps[3];
  q = pq[0] + pq[1] + pq[2] + pq[3];
  const float mean = s * (1.f/1024.f);
  const float var  = q * (1.f/1024.f) - mean*mean;
  const float rstd = rsqrtf(var + 1e-5f);
  f32x4 g4 = *(const f32x4*)(G  + t*4);
  f32x4 b4 = *(const f32x4*)(Bv + t*4);
  f32x4 o;
#pragma unroll
  for (int j = 0; j < 4; j++) o[j] = (v[j] - mean) * rstd * g4[j] + b4[j];
  *(f32x4*)(Of + base) = o;
  if (WB16){
    s16x4 ob;
#pragma unroll
    for (int j = 0; j < 4; j++) ob[j] = (short)f2bn(o[j]);
    *(s16x4*)(Ob + base) = ob;
  }
}

// ---------------- launch ----------------
extern "C" void kernel_launch(void* const* d_in, const int* in_sizes, int n_in,
                              void* d_out, int out_size, void* d_ws, size_t ws_size,
                              hipStream_t stream)
{
  const float* x   = (const float*)d_in[0];
  const float* enc = (const float*)d_in[1];
  const float* aw[8]; const float* ab[8];
  for (int i = 0; i < 8; i++){ aw[i] = (const float*)d_in[2 + 2*i]; ab[i] = (const float*)d_in[3 + 2*i]; }
  const float* w1 = (const float*)d_in[18]; const float* b1 = (const float*)d_in[19];
  const float* w2 = (const float*)d_in[20]; const float* b2 = (const float*)d_in[21];
  const float* lg[3] = {(const float*)d_in[22], (const float*)d_in[24], (const float*)d_in[26]};
  const float* lb[3] = {(const float*)d_in[23], (const float*)d_in[25], (const float*)d_in[27]};
  float* out = (float*)d_out;

  const size_t MB = 1024ull * 1024ull;
  if (ws_size < 129 * MB) return;
  char* ws = (char*)d_ws;
  ushort* wqkv = (ushort*)(ws + 0*MB);
  ushort* wcq  = (ushort*)(ws + 6*MB);
  ushort* wkv  = (ushort*)(ws + 8*MB);
  ushort* wo1w = (ushort*)(ws + 12*MB);
  ushort* wo2w = (ushort*)(ws + 14*MB);
  ushort* w1b  = (ushort*)(ws + 16*MB);
  ushort* w2b  = (ushort*)(ws + 24*MB);
  ushort* xb   = (ushort*)(ws + 32*MB);     // dead after QKV
  ushort* encb = (ushort*)(ws + 40*MB);     // dead after cKV
  ushort* attb = (ushort*)(ws + 48*MB);
  float*  proj = (float*)(ws + 56*MB);
  float*  x1f  = (float*)(ws + 72*MB);
  ushort* xab  = (ushort*)(ws + 88*MB);
  // phase region [96MB,128MB)
  ushort* QKVb    = (ushort*)(ws + 96*MB);
  ushort* Vt1     = (ushort*)(ws + 120*MB);
  ushort* crossQb = (ushort*)(ws + 96*MB);
  ushort* encKVb  = (ushort*)(ws + 104*MB);
  ushort* Vt2     = (ushort*)(ws + 120*MB);
  ushort* hb      = (ushort*)(ws + 96*MB);   // FFN1 out (live through FFN2)
  float*  pWO     = (float*)(ws + 96*MB);    // wo split-K partial
  float*  pFF     = (float*)(ws + 32*MB);    // FFN2 partial (xb/encb dead)
  float*  bqkv = (float*)(ws + 128*MB);
  float*  bkv  = (float*)(ws + 128*MB + 16384);

  const long long ssWO  = ((long long)(96 - 56) * (long long)MB) / 4;
  const long long ssFFN = ((long long)(32 - 56) * (long long)MB) / 4;   // negative offset

  // ---- fused conversions ----
  ConvArgs ca;
  const float* srcs[17] = { x, enc, aw[0], aw[1], aw[2], aw[3], aw[4], aw[5], aw[6], aw[7],
                            w1, w2, ab[0], ab[1], ab[2], ab[5], ab[6] };
  void* dsts[17] = { xb, encb, wqkv, wqkv + 1048576, wqkv + 2097152, wo1w, wcq, wkv, wkv + 1048576, wo2w,
                     w1b, w2b, bqkv, bqkv + 1024, bqkv + 2048, bkv, bkv + 1024 };
  int nels[17] = { 4194304, 4194304, 1048576, 1048576, 1048576, 1048576, 1048576, 1048576, 1048576, 1048576,
                   4194304, 4194304, 1024, 1024, 1024, 1024, 1024 };
  int acc_blk = 0;
  for (int i = 0; i < 17; i++){
    ca.src[i] = srcs[i]; ca.dst[i] = dsts[i]; ca.nel[i] = nels[i];
    acc_blk += (nels[i] + 2047) / 2048;
    ca.blk_end[i] = acc_blk;
  }
  ca.f32mask = 0x1F000u;
  k_conv<<<acc_blk, 256, 0, stream>>>(ca);

  // ---- self-attention block ----
  k_gemm256<0><<<dim3(12,16), 512, 0, stream>>>(xb, wqkv, bqkv, QKVb, 3072, 1024, 1024, 1024, 1024, SCALE_C);
  k_vt<<<dim3(32,16,2), 256, 0, stream>>>(QKVb + 2048, Vt1, 3072, 2048);
  k_attn<true><<<dim3(32,8), 256, 0, stream>>>(QKVb, QKVb + 1024, Vt1, attb, 3072, 3072, 2048, 2048);
  k_gemmS<<<dim3(8,32,2), 256, 0, stream>>>(attb, wo1w, ab[3], proj, 4096, 1024, 512, 1024, 1024, ssWO);
  k_ln<true><<<4096, 256, 0, stream>>>(x, proj, pWO, lg[0], lb[0], x1f, xab);

  // ---- cross-attention block ----
  k_gemm<<<dim3(8,32), 256, 0, stream>>>(xab, wcq, ab[4], crossQb, 4096, 1024, 1024, 1024, 1024, SCALE_C);
  k_gemm256<0><<<dim3(8,16), 512, 0, stream>>>(encb, wkv, bkv, encKVb, 2048, 1024, 1024, 1024, 0, 1.f);
  k_vt<<<dim3(32,16,2), 256, 0, stream>>>(encKVb + 1024, Vt2, 2048, 2048);
  k_attn<false><<<dim3(32,16), 256, 0, stream>>>(crossQb, encKVb, Vt2, attb, 1024, 2048, 2048, 2048);
  k_gemmS<<<dim3(8,32,2), 256, 0, stream>>>(attb, wo2w, ab[7], proj, 4096, 1024, 512, 1024, 1024, ssWO);
  k_ln<true><<<4096, 256, 0, stream>>>(x1f, proj, pWO, lg[1], lb[1], x1f, xab);   // x1f -> x2 in place

  // ---- FFN block ----
  k_gemm256<2><<<dim3(16,16), 512, 0, stream>>>(xab, w1b, b1, hb, 4096, 1024, 1024, 1024, 0, 1.f);
  k_gemmS<<<dim3(8,32,2), 256, 0, stream>>>(hb, w2b, b2, proj, 4096, 1024, 2048, 4096, 4096, ssFFN);
  k_ln<false><<<4096, 256, 0, stream>>>(x1f, proj, pFF, lg[2], lb[2], out, nullptr);
}

// Round 13
// 398.581 us; speedup vs baseline: 1.0497x; 1.0497x over previous
//
#include <hip/hip_runtime.h>
#include <hip/hip_bf16.h>
#include <stdint.h>

typedef __attribute__((ext_vector_type(8)))  short s16x8;
typedef __attribute__((ext_vector_type(4)))  short s16x4;
typedef __attribute__((ext_vector_type(4)))  float f32x4;

#define DEV static __device__ __forceinline__

DEV ushort f2bu(float f){
  unsigned u = __builtin_bit_cast(unsigned, f);
  return (ushort)((u + 0x7fffu + ((u >> 16) & 1u)) >> 16);   // RNE f32->bf16
}
DEV ushort f2bn(float f){
  return __builtin_bit_cast(ushort, __float2bfloat16(f));
}

DEV void gload16(const void* g, void* l){
  __builtin_amdgcn_global_load_lds((const __attribute__((address_space(1))) void*)g,
                                   (__attribute__((address_space(3))) void*)l, 16, 0, 0);
}

#define SCALE_C 0.18033688f   // 0.125 * log2(e), folded into Q projections

// ---------------- fused f32->bf16 conversions + f32 bias concat ----------------
struct ConvArgs {
  const float* src[17];
  void*        dst[17];
  int blk_end[17];
  int nel[17];
  unsigned f32mask;
};

__global__ void __launch_bounds__(256) k_conv(ConvArgs a){
  int bi = blockIdx.x, seg = 0;
  while (bi >= a.blk_end[seg]) seg++;
  int b0 = seg ? a.blk_end[seg-1] : 0;
  long off = (long)(bi - b0)*2048 + (long)threadIdx.x*8;
  if (off >= a.nel[seg]) return;
  const float* s = a.src[seg] + off;
  f32x4 v0 = *(const f32x4*)s;
  f32x4 v1 = *(const f32x4*)(s+4);
  if ((a.f32mask >> seg) & 1u){
    float* d = (float*)a.dst[seg] + off;
    *(f32x4*)d = v0; *(f32x4*)(d+4) = v1;
  } else {
    ushort* d = (ushort*)a.dst[seg] + off;
    s16x8 o;
#pragma unroll
    for (int j = 0; j < 4; j++){ o[j] = (short)f2bu(v0[j]); o[4+j] = (short)f2bu(v1[j]); }
    *(s16x8*)d = o;
  }
}

// ---------------- batched 128x128 dbuf GEMM: cQ (256 blocks) + cross-KV (512 blocks) ----------------
__global__ void __launch_bounds__(256) k_gemmB(const ushort* __restrict__ A0, const ushort* __restrict__ W0,
    const float* __restrict__ b0, ushort* __restrict__ C0,
    const ushort* __restrict__ A1, const ushort* __restrict__ W1,
    const float* __restrict__ b1, ushort* __restrict__ C1, float scale0)
{
  __shared__ __align__(16) ushort lsA[2][128*64];
  __shared__ __align__(16) ushort lsB[2][128*64];
  const int t = threadIdx.x, w = t >> 6, u = t & 63, lr = u & 15, lk = u >> 4;
  const int bid = blockIdx.x;
  const ushort *A, *W; const float* bias; ushort* C; int N, n0, m0; float scale;
  if (bid < 256){ A = A0; W = W0; bias = b0; C = C0; N = 1024; n0 = (bid & 7)*128;  m0 = (bid >> 3)*128; scale = scale0; }
  else { int i2 = bid - 256; A = A1; W = W1; bias = b1; C = C1; N = 2048; n0 = (i2 & 15)*128; m0 = (i2 >> 4)*128; scale = 1.f; }
  const int wm = w >> 1, wn = w & 1;
  const int rA = t >> 3, c8 = (t & 7) * 8;
  const ushort* Ap = A + (size_t)(m0 + rA) * 1024 + c8;
  const ushort* Wp = W + (size_t)(n0 + rA) * 1024 + c8;
  f32x4 acc[4][4] = {};

  auto stage = [&](int k0, int buf){
#pragma unroll
    for (int j = 0; j < 4; j++){
      gload16(Ap + (size_t)j*32*1024 + k0, &lsA[buf][0] + j*2048 + w*512);
      gload16(Wp + (size_t)j*32*1024 + k0, &lsB[buf][0] + j*2048 + w*512);
    }
  };
  stage(0, 0);
  for (int tk = 0; tk < 16; ++tk){
    __syncthreads();
    if (tk + 1 < 16) stage((tk + 1) << 6, (tk + 1) & 1);
    const ushort* La = &lsA[tk & 1][0];
    const ushort* Lb = &lsB[tk & 1][0];
#pragma unroll
    for (int ks = 0; ks < 2; ks++){
      s16x8 af[4], bfr[4];
#pragma unroll
      for (int i = 0; i < 4; i++) af[i]  = *(const s16x8*)(La + (wm*64 + i*16 + lr)*64 + ks*32 + lk*8);
#pragma unroll
      for (int i = 0; i < 4; i++) bfr[i] = *(const s16x8*)(Lb + (wn*64 + i*16 + lr)*64 + ks*32 + lk*8);
#pragma unroll
      for (int mi = 0; mi < 4; mi++)
#pragma unroll
        for (int ni = 0; ni < 4; ni++)
          acc[mi][ni] = __builtin_amdgcn_mfma_f32_16x16x32_bf16(af[mi], bfr[ni], acc[mi][ni], 0, 0, 0);
    }
  }

#pragma unroll
  for (int mi = 0; mi < 4; mi++){
#pragma unroll
    for (int ni = 0; ni < 4; ni++){
      const int row = m0 + wm*64 + mi*16 + lk*4;
      const int col = n0 + wn*64 + ni*16 + lr;
      const float bv = bias[col];
#pragma unroll
      for (int i = 0; i < 4; i++){
        float v = (acc[mi][ni][i] + bv) * scale;
        C[(size_t)(row + i) * N + col] = f2bn(v);
      }
    }
  }
}

// ---------------- 128x128 dbuf GEMM, split-K f32 out (wo1/wo2/FFN2) ----------------
__global__ void __launch_bounds__(256) k_gemmS(const ushort* __restrict__ A, const ushort* __restrict__ W,
    const float* __restrict__ bias, float* __restrict__ Cf,
    int M, int N, int Kext, int lda, int ldb, long long sstride)
{
  __shared__ __align__(16) ushort lsA[2][128*64];
  __shared__ __align__(16) ushort lsB[2][128*64];
  const int t = threadIdx.x, w = t >> 6, u = t & 63, lr = u & 15, lk = u >> 4;
  const int m0 = blockIdx.y * 128, n0 = blockIdx.x * 128;
  const int s = blockIdx.z;
  const int wm = w >> 1, wn = w & 1;
  const int rA = t >> 3, c8 = (t & 7) * 8;
  const ushort* Ap = A + (size_t)(m0 + rA) * lda + (size_t)s * Kext + c8;
  const ushort* Wp = W + (size_t)(n0 + rA) * ldb + (size_t)s * Kext + c8;
  if (s){ bias = nullptr; Cf += sstride; }
  f32x4 acc[4][4] = {};
  const int nk = Kext >> 6;

  auto stage = [&](int k0, int buf){
#pragma unroll
    for (int j = 0; j < 4; j++){
      gload16(Ap + (size_t)j*32*lda + k0, &lsA[buf][0] + j*2048 + w*512);
      gload16(Wp + (size_t)j*32*ldb + k0, &lsB[buf][0] + j*2048 + w*512);
    }
  };
  stage(0, 0);
  for (int tk = 0; tk < nk; ++tk){
    __syncthreads();
    if (tk + 1 < nk) stage((tk + 1) << 6, (tk + 1) & 1);
    const ushort* La = &lsA[tk & 1][0];
    const ushort* Lb = &lsB[tk & 1][0];
#pragma unroll
    for (int ks = 0; ks < 2; ks++){
      s16x8 af[4], bfr[4];
#pragma unroll
      for (int i = 0; i < 4; i++) af[i]  = *(const s16x8*)(La + (wm*64 + i*16 + lr)*64 + ks*32 + lk*8);
#pragma unroll
      for (int i = 0; i < 4; i++) bfr[i] = *(const s16x8*)(Lb + (wn*64 + i*16 + lr)*64 + ks*32 + lk*8);
#pragma unroll
      for (int mi = 0; mi < 4; mi++)
#pragma unroll
        for (int ni = 0; ni < 4; ni++)
          acc[mi][ni] = __builtin_amdgcn_mfma_f32_16x16x32_bf16(af[mi], bfr[ni], acc[mi][ni], 0, 0, 0);
    }
  }

#pragma unroll
  for (int mi = 0; mi < 4; mi++){
#pragma unroll
    for (int ni = 0; ni < 4; ni++){
      const int row = m0 + wm*64 + mi*16 + lk*4;
      const int col = n0 + wn*64 + ni*16 + lr;
      const float bv = bias ? bias[col] : 0.f;
#pragma unroll
      for (int i = 0; i < 4; i++)
        Cf[(size_t)(row + i) * N + col] = acc[mi][ni][i] + bv;
    }
  }
}

// ---------------- 256x256 8-phase GEMM (T2+T3+T4+T5) ----------------
// MODE 0: bf16 out, cols<scaleLim scaled; MODE 2: relu + bf16 out.
template<int MODE>
__global__ void __launch_bounds__(512, 1) k_gemm256(const ushort* __restrict__ A, const ushort* __restrict__ W,
    const float* __restrict__ bias, ushort* __restrict__ Cb,
    int N, int Ktot, int lda, int ldb, int scaleLim, float scale)
{
  __shared__ __align__(16) ushort lsA[2][256*64];
  __shared__ __align__(16) ushort lsB[2][256*64];
  const int t = threadIdx.x, w = t >> 6, u = t & 63, lr = u & 15, lk = u >> 4;
  const int gx = gridDim.x;
  const int nwg = gx * gridDim.y;
  const int id = blockIdx.y * gx + blockIdx.x;
  const int swz = (id & 7) * (nwg >> 3) + (id >> 3);      // bijective: nwg % 8 == 0
  const int n0 = (swz % gx) * 256, m0 = (swz / gx) * 256;
  const int wm = w >> 2, wn = w & 3;
  const int nt = Ktot >> 6;

  const int r0 = w*8 + (u >> 3), cc = u & 7;
  const int csw = 8 * (cc ^ (r0 & 7));
  const ushort* Ap = A + (size_t)(m0 + r0) * lda + csw;
  const ushort* Wp = W + (size_t)(n0 + r0) * ldb + csw;

  f32x4 acc[8][4] = {};
  const int swl = lr & 7;
  s16x8 afr[4], bfr[4];

#pragma unroll
  for (int j = 0; j < 4; j++){
    gload16(Ap + (size_t)(64*j)*lda, &lsA[0][0] + w*512 + j*4096);
    gload16(Wp + (size_t)(64*j)*ldb, &lsB[0][0] + w*512 + j*4096);
  }
  asm volatile("s_waitcnt vmcnt(0)" ::: "memory");
  __builtin_amdgcn_s_barrier();

  for (int tk = 0; tk < nt; ++tk){
    const char* La = (const char*)&lsA[tk & 1][0];
    const char* Lb = (const char*)&lsB[tk & 1][0];
    ushort* dA = &lsA[(tk & 1) ^ 1][0] + w*512;
    ushort* dB = &lsB[(tk & 1) ^ 1][0] + w*512;
    const bool pf = (tk + 1 < nt);
    const size_t k1 = (size_t)(tk + 1) << 6;

    // ---- phase 1 ----
#pragma unroll
    for (int i = 0; i < 4; i++)
      afr[i] = *(const s16x8*)(La + (wm*128 + i*16 + lr)*128 + ((lk ^ swl) * 16));
#pragma unroll
    for (int i = 0; i < 4; i++)
      bfr[i] = *(const s16x8*)(Lb + (wn*64 + i*16 + lr)*128 + ((lk ^ swl) * 16));
    if (pf){
      gload16(Ap + k1, dA);
      gload16(Wp + k1, dB);
      gload16(Ap + (size_t)64*lda + k1, dA + 4096);
      gload16(Wp + (size_t)64*ldb + k1, dB + 4096);
    }
    __builtin_amdgcn_s_barrier();
    asm volatile("s_waitcnt lgkmcnt(0)" ::: "memory");
    __builtin_amdgcn_s_setprio(1);
#pragma unroll
    for (int mi = 0; mi < 4; mi++)
#pragma unroll
      for (int ni = 0; ni < 4; ni++)
        acc[mi][ni] = __builtin_amdgcn_mfma_f32_16x16x32_bf16(afr[mi], bfr[ni], acc[mi][ni], 0, 0, 0);
    __builtin_amdgcn_s_setprio(0);
    __builtin_amdgcn_s_barrier();

    // ---- phase 2 ----
#pragma unroll
    for (int i = 0; i < 4; i++)
      afr[i] = *(const s16x8*)(La + (wm*128 + 64 + i*16 + lr)*128 + ((lk ^ swl) * 16));
    if (pf){
      gload16(Ap + (size_t)128*lda + k1, dA + 8192);
      gload16(Wp + (size_t)128*ldb + k1, dB + 8192);
      gload16(Ap + (size_t)192*lda + k1, dA + 12288);
      gload16(Wp + (size_t)192*ldb + k1, dB + 12288);
    }
    __builtin_amdgcn_s_barrier();
    asm volatile("s_waitcnt lgkmcnt(0)" ::: "memory");
    __builtin_amdgcn_s_setprio(1);
#pragma unroll
    for (int mi = 0; mi < 4; mi++)
#pragma unroll
      for (int ni = 0; ni < 4; ni++)
        acc[4+mi][ni] = __builtin_amdgcn_mfma_f32_16x16x32_bf16(afr[mi], bfr[ni], acc[4+mi][ni], 0, 0, 0);
    __builtin_amdgcn_s_setprio(0);
    __builtin_amdgcn_s_barrier();

    // ---- phase 3 ----
#pragma unroll
    for (int i = 0; i < 4; i++)
      afr[i] = *(const s16x8*)(La + (wm*128 + i*16 + lr)*128 + (((4 + lk) ^ swl) * 16));
#pragma unroll
    for (int i = 0; i < 4; i++)
      bfr[i] = *(const s16x8*)(Lb + (wn*64 + i*16 + lr)*128 + (((4 + lk) ^ swl) * 16));
    __builtin_amdgcn_s_barrier();
    asm volatile("s_waitcnt lgkmcnt(0)" ::: "memory");
    __builtin_amdgcn_s_setprio(1);
#pragma unroll
    for (int mi = 0; mi < 4; mi++)
#pragma unroll
      for (int ni = 0; ni < 4; ni++)
        acc[mi][ni] = __builtin_amdgcn_mfma_f32_16x16x32_bf16(afr[mi], bfr[ni], acc[mi][ni], 0, 0, 0);
    __builtin_amdgcn_s_setprio(0);
    __builtin_amdgcn_s_barrier();

    // ---- phase 4 ----
#pragma unroll
    for (int i = 0; i < 4; i++)
      afr[i] = *(const s16x8*)(La + (wm*128 + 64 + i*16 + lr)*128 + (((4 + lk) ^ swl) * 16));
    __builtin_amdgcn_s_barrier();
    asm volatile("s_waitcnt lgkmcnt(0)" ::: "memory");
    __builtin_amdgcn_s_setprio(1);
#pragma unroll
    for (int mi = 0; mi < 4; mi++)
#pragma unroll
      for (int ni = 0; ni < 4; ni++)
        acc[4+mi][ni] = __builtin_amdgcn_mfma_f32_16x16x32_bf16(afr[mi], bfr[ni], acc[4+mi][ni], 0, 0, 0);
    __builtin_amdgcn_s_setprio(0);
    asm volatile("s_waitcnt vmcnt(0)" ::: "memory");
    __builtin_amdgcn_s_barrier();
  }

#pragma unroll
  for (int mi = 0; mi < 8; mi++){
#pragma unroll
    for (int ni = 0; ni < 4; ni++){
      const int row = m0 + wm*128 + mi*16 + lk*4;
      const int col = n0 + wn*64 + ni*16 + lr;
      const float bv = bias[col];
#pragma unroll
      for (int i = 0; i < 4; i++){
        float v = acc[mi][ni][i] + bv;
        if (MODE == 2) v = fmaxf(v, 0.f);
        if (MODE == 0 && col < scaleLim) v *= scale;
        Cb[(size_t)(row + i) * N + col] = f2bn(v);
      }
    }
  }
}

// ---------------- V transpose: [B,S,(stride)] head-block -> Vt[B,H,64,S] ----------------
__global__ void __launch_bounds__(256) k_vt(const ushort* __restrict__ V, ushort* __restrict__ Vt,
                                            int stride, int S)
{
  __shared__ ushort tile[64][72];
  const int st = blockIdx.x*64, h = blockIdx.y, b = blockIdx.z;
  const int r = threadIdx.x >> 3, c8 = (threadIdx.x & 7)*8;
#pragma unroll
  for (int j = 0; j < 2; j++){
    int s = r + j*32;
    s16x8 v = *(const s16x8*)(V + (size_t)(b*S + st + s)*stride + h*64 + c8);
    *(s16x8*)&tile[s][c8] = v;
  }
  __syncthreads();
#pragma unroll
  for (int j = 0; j < 2; j++){
    int d = r + j*32;
    s16x8 o;
#pragma unroll
    for (int e = 0; e < 8; e++) o[e] = tile[c8+e][d];
    *(s16x8*)(Vt + ((size_t)((b*16 + h)*64 + d))*S + st + c8) = o;
  }
}

// ---------------- flash attention: 8 waves, QBLK=128, KVBLK=64 ----------------
// Q pre-scaled by 0.125*log2(e); m=0 softmax (exp2 direct).
// Row-sum computed by the MATRIX pipe: lsum = mfma(P_frag, ONES) accumulates the softmax
// denominator in the same C-layout as O -> zero cross-lane reduction.
// CAUSAL: grid (32, 8): q-tiles {15-y, y}. cross: grid (32, 16).
template<bool CAUSAL>
__global__ void __launch_bounds__(512) k_attn(const ushort* __restrict__ Q, const ushort* __restrict__ Kg,
    const ushort* __restrict__ Vt, ushort* __restrict__ O, int sQ, int sK, int SQ, int SKV)
{
  __shared__ __align__(16) ushort Kl[2][64*64];
  __shared__ __align__(16) ushort Vl[2][64*64];
  __shared__ __align__(16) ushort Pl[8][16*64];
  const int t = threadIdx.x, w = t >> 6, u = t & 63, lr = u & 15, lk = u >> 4;
  const int hb = blockIdx.x;
  const int b = hb >> 4, h = hb & 15;
  const int srow = t >> 3, scol = t & 7;
  const size_t kvbase = (size_t)b * SKV;
  const size_t vtbase = (size_t)((b*16 + h)*64);
  char* Pc = (char*)&Pl[w][0];
  const int swzq = (lr & 7) << 4;

  s16x8 ONES;
#pragma unroll
  for (int j = 0; j < 8; j++) ONES[j] = (short)0x3F80;   // bf16 1.0

  auto stage = [&](int kt, int buf){
    gload16(Kg + (kvbase + kt*64 + srow)*sK + h*64 + 8*(scol ^ (srow & 7)), &Kl[buf][0] + w*512);
    gload16(Vt + (vtbase + srow)*SKV + kt*64 + 8*(scol ^ (srow & 7)), &Vl[buf][0] + w*512);
  };

  const int NREP = CAUSAL ? 2 : 1;
#pragma unroll 1
  for (int rep = 0; rep < NREP; rep++){
    const int qt = CAUSAL ? (rep ? (int)blockIdx.y : (int)(2*gridDim.y - 1 - blockIdx.y))
                          : (int)blockIdx.y;
    const int q0 = qt * 128;

    const ushort* qp = Q + (size_t)(b*SQ + q0 + w*16 + lr) * sQ + h*64 + lk*8;
    s16x8 qf0 = *(const s16x8*)qp;
    s16x8 qf1 = *(const s16x8*)(qp + 32);

    f32x4 oacc[4] = {};
    f32x4 lsum = {};
    const int nkt = CAUSAL ? (2*qt + 2) : (SKV >> 6);

    stage(0, 0);
    __syncthreads();

    for (int kt = 0; kt < nkt; kt++){
      const int buf = kt & 1;
      if (kt + 1 < nkt) stage(kt + 1, buf ^ 1);
      char* Kc = (char*)&Kl[buf][0];
      char* Vc = (char*)&Vl[buf][0];

      // S^T = K @ Q : lane holds S[q=lr][key = 16ni + 4lk + i] (already *0.125*log2e)
      f32x4 sacc[4] = {};
      __builtin_amdgcn_s_setprio(1);
#pragma unroll
      for (int ks = 0; ks < 2; ks++){
        s16x8 qf = ks ? qf1 : qf0;
#pragma unroll
        for (int ni = 0; ni < 4; ni++){
          int key = ni*16 + lr;
          s16x8 kf = *(const s16x8*)(Kc + key*128 + ((ks*64 + lk*16) ^ ((key & 7) << 4)));
          sacc[ni] = __builtin_amdgcn_mfma_f32_16x16x32_bf16(kf, qf, sacc[ni], 0, 0, 0);
        }
      }
      __builtin_amdgcn_s_setprio(0);
      if (CAUSAL && kt >= 2*qt){
        const int koff = kt*64 - q0;
#pragma unroll
        for (int ni = 0; ni < 4; ni++)
#pragma unroll
          for (int i = 0; i < 4; i++)
            if (koff + 16*ni + lk*4 + i > w*16 + lr) sacc[ni][i] = -1e30f;
      }

#pragma unroll
      for (int ni = 0; ni < 4; ni++)
#pragma unroll
        for (int i = 0; i < 4; i++) sacc[ni][i] = __builtin_exp2f(sacc[ni][i]);

#pragma unroll
      for (int ni = 0; ni < 4; ni++){
        s16x4 pk;
#pragma unroll
        for (int i = 0; i < 4; i++) pk[i] = (short)f2bn(sacc[ni][i]);
        *(s16x4*)(Pc + lr*128 + ((32*ni + 8*lk) ^ swzq)) = pk;
      }

      __builtin_amdgcn_s_setprio(1);
#pragma unroll
      for (int ks = 0; ks < 2; ks++){
        s16x8 pf = *(const s16x8*)(Pc + lr*128 + ((ks*64 + lk*16) ^ swzq));
        lsum = __builtin_amdgcn_mfma_f32_16x16x32_bf16(pf, ONES, lsum, 0, 0, 0);
#pragma unroll
        for (int ni = 0; ni < 4; ni++){
          int d = ni*16 + lr;
          s16x8 vf = *(const s16x8*)(Vc + d*128 + ((ks*64 + lk*16) ^ ((d & 7) << 4)));
          oacc[ni] = __builtin_amdgcn_mfma_f32_16x16x32_bf16(pf, vf, oacc[ni], 0, 0, 0);
        }
      }
      __builtin_amdgcn_s_setprio(0);
      __syncthreads();
    }

    // lsum[i] already holds the denominator for row q = q0 + w*16 + lk*4 + i
    float invl[4];
#pragma unroll
    for (int i = 0; i < 4; i++) invl[i] = 1.f / lsum[i];
#pragma unroll
    for (int ni = 0; ni < 4; ni++)
#pragma unroll
      for (int i = 0; i < 4; i++)
        O[(size_t)(b*SQ + q0 + w*16 + lk*4 + i)*1024 + h*64 + ni*16 + lr] = f2bn(oacc[ni][i] * invl[i]);
  }
}

// ---------------- residual + LayerNorm (E=1024), optional second partial ----------------
template<bool WB16>
__global__ void __launch_bounds__(256) k_ln(const float* __restrict__ R, const float* __restrict__ P,
    const float* __restrict__ P2, const float* __restrict__ G, const float* __restrict__ Bv,
    float* __restrict__ Of, ushort* __restrict__ Ob)
{
  const int row = blockIdx.x, t = threadIdx.x, w = t >> 6, u = t & 63;
  const size_t base = (size_t)row * 1024 + t * 4;
  f32x4 r = *(const f32x4*)(R + base);
  f32x4 p = *(const f32x4*)(P + base);
  f32x4 v = r + p;
  if (P2){ f32x4 p2 = *(const f32x4*)(P2 + base); v += p2; }
  float s = 0.f, q = 0.f;
#pragma unroll
  for (int j = 0; j < 4; j++){ s += v[j]; q += v[j]*v[j]; }
#pragma unroll
  for (int md = 1; md < 64; md <<= 1){ s += __shfl_xor(s, md); q += __shfl_xor(q, md); }
  __shared__ float ps[4], pq[4];
  if (u == 0){ ps[w] = s; pq[w] = q; }
  __syncthreads();
  s = ps[0] + ps[1] + ps[2] + ps[3];
  q = pq[0] + pq[1] + pq[2] + pq[3];
  const float mean = s * (1.f/1024.f);
  const float var  = q * (1.f/1024.f) - mean*mean;
  const float rstd = rsqrtf(var + 1e-5f);
  f32x4 g4 = *(const f32x4*)(G  + t*4);
  f32x4 b4 = *(const f32x4*)(Bv + t*4);
  f32x4 o;
#pragma unroll
  for (int j = 0; j < 4; j++) o[j] = (v[j] - mean) * rstd * g4[j] + b4[j];
  *(f32x4*)(Of + base) = o;
  if (WB16){
    s16x4 ob;
#pragma unroll
    for (int j = 0; j < 4; j++) ob[j] = (short)f2bn(o[j]);
    *(s16x4*)(Ob + base) = ob;
  }
}

// ---------------- launch ----------------
extern "C" void kernel_launch(void* const* d_in, const int* in_sizes, int n_in,
                              void* d_out, int out_size, void* d_ws, size_t ws_size,
                              hipStream_t stream)
{
  const float* x   = (const float*)d_in[0];
  const float* enc = (const float*)d_in[1];
  const float* aw[8]; const float* ab[8];
  for (int i = 0; i < 8; i++){ aw[i] = (const float*)d_in[2 + 2*i]; ab[i] = (const float*)d_in[3 + 2*i]; }
  const float* w1 = (const float*)d_in[18]; const float* b1 = (const float*)d_in[19];
  const float* w2 = (const float*)d_in[20]; const float* b2 = (const float*)d_in[21];
  const float* lg[3] = {(const float*)d_in[22], (const float*)d_in[24], (const float*)d_in[26]};
  const float* lb[3] = {(const float*)d_in[23], (const float*)d_in[25], (const float*)d_in[27]};
  float* out = (float*)d_out;

  const size_t MB = 1024ull * 1024ull;
  if (ws_size < 129 * MB) return;
  char* ws = (char*)d_ws;
  ushort* wqkv = (ushort*)(ws + 0*MB);
  ushort* wcq  = (ushort*)(ws + 6*MB);
  ushort* wkv  = (ushort*)(ws + 8*MB);
  ushort* wo1w = (ushort*)(ws + 12*MB);
  ushort* wo2w = (ushort*)(ws + 14*MB);
  ushort* w1b  = (ushort*)(ws + 16*MB);
  ushort* w2b  = (ushort*)(ws + 24*MB);
  ushort* xb   = (ushort*)(ws + 32*MB);     // dead after QKV
  ushort* encb = (ushort*)(ws + 40*MB);     // dead after cKV
  ushort* attb = (ushort*)(ws + 48*MB);
  float*  proj = (float*)(ws + 56*MB);
  float*  x1f  = (float*)(ws + 72*MB);
  ushort* xab  = (ushort*)(ws + 88*MB);
  // phase region [96MB,128MB)
  ushort* QKVb    = (ushort*)(ws + 96*MB);
  ushort* Vt1     = (ushort*)(ws + 120*MB);
  ushort* crossQb = (ushort*)(ws + 96*MB);
  ushort* encKVb  = (ushort*)(ws + 104*MB);
  ushort* Vt2     = (ushort*)(ws + 120*MB);
  ushort* hb      = (ushort*)(ws + 96*MB);   // FFN1 out (live through FFN2)
  float*  pWO     = (float*)(ws + 96*MB);    // wo split-K partial (phase region dead then)
  float*  pFF     = (float*)(ws + 32*MB);    // FFN2 partial (xb/encb dead)
  float*  bqkv = (float*)(ws + 128*MB);
  float*  bkv  = (float*)(ws + 128*MB + 16384);

  const long long ssWO  = ((long long)(96 - 56) * (long long)MB) / 4;
  const long long ssFFN = ((long long)(32 - 56) * (long long)MB) / 4;   // negative offset

  // ---- fused conversions ----
  ConvArgs ca;
  const float* srcs[17] = { x, enc, aw[0], aw[1], aw[2], aw[3], aw[4], aw[5], aw[6], aw[7],
                            w1, w2, ab[0], ab[1], ab[2], ab[5], ab[6] };
  void* dsts[17] = { xb, encb, wqkv, wqkv + 1048576, wqkv + 2097152, wo1w, wcq, wkv, wkv + 1048576, wo2w,
                     w1b, w2b, bqkv, bqkv + 1024, bqkv + 2048, bkv, bkv + 1024 };
  int nels[17] = { 4194304, 4194304, 1048576, 1048576, 1048576, 1048576, 1048576, 1048576, 1048576, 1048576,
                   4194304, 4194304, 1024, 1024, 1024, 1024, 1024 };
  int acc_blk = 0;
  for (int i = 0; i < 17; i++){
    ca.src[i] = srcs[i]; ca.dst[i] = dsts[i]; ca.nel[i] = nels[i];
    acc_blk += (nels[i] + 2047) / 2048;
    ca.blk_end[i] = acc_blk;
  }
  ca.f32mask = 0x1F000u;
  k_conv<<<acc_blk, 256, 0, stream>>>(ca);

  // ---- self-attention block ----
  k_gemm256<0><<<dim3(12,16), 512, 0, stream>>>(xb, wqkv, bqkv, QKVb, 3072, 1024, 1024, 1024, 1024, SCALE_C);
  k_vt<<<dim3(32,16,2), 256, 0, stream>>>(QKVb + 2048, Vt1, 3072, 2048);
  k_attn<true><<<dim3(32,8), 512, 0, stream>>>(QKVb, QKVb + 1024, Vt1, attb, 3072, 3072, 2048, 2048);
  k_gemmS<<<dim3(8,32,2), 256, 0, stream>>>(attb, wo1w, ab[3], proj, 4096, 1024, 512, 1024, 1024, ssWO);
  k_ln<true><<<4096, 256, 0, stream>>>(x, proj, pWO, lg[0], lb[0], x1f, xab);

  // ---- cross-attention block: cQ + cKV fused in one dispatch (768 blocks = 3/CU) ----
  k_gemmB<<<768, 256, 0, stream>>>(xab, wcq, ab[4], crossQb, encb, wkv, bkv, encKVb, SCALE_C);
  k_vt<<<dim3(32,16,2), 256, 0, stream>>>(encKVb + 1024, Vt2, 2048, 2048);
  k_attn<false><<<dim3(32,16), 512, 0, stream>>>(crossQb, encKVb, Vt2, attb, 1024, 2048, 2048, 2048);
  k_gemmS<<<dim3(8,32,2), 256, 0, stream>>>(attb, wo2w, ab[7], proj, 4096, 1024, 512, 1024, 1024, ssWO);
  k_ln<true><<<4096, 256, 0, stream>>>(x1f, proj, pWO, lg[1], lb[1], x1f, xab);   // x1f -> x2 in place

  // ---- FFN block ----
  k_gemm256<2><<<dim3(16,16), 512, 0, stream>>>(xab, w1b, b1, hb, 4096, 1024, 1024, 1024, 0, 1.f);
  k_gemmS<<<dim3(8,32,2), 256, 0, stream>>>(hb, w2b, b2, proj, 4096, 1024, 2048, 4096, 4096, ssFFN);
  k_ln<false><<<4096, 256, 0, stream>>>(x1f, proj, pFF, lg[2], lb[2], out, nullptr);
}

// Round 14
// 387.950 us; speedup vs baseline: 1.0785x; 1.0274x over previous
//
#include <hip/hip_runtime.h>
#include <hip/hip_bf16.h>
#include <stdint.h>

typedef __attribute__((ext_vector_type(8)))  short s16x8;
typedef __attribute__((ext_vector_type(4)))  short s16x4;
typedef __attribute__((ext_vector_type(4)))  float f32x4;

#define DEV static __device__ __forceinline__

DEV ushort f2bu(float f){
  unsigned u = __builtin_bit_cast(unsigned, f);
  return (ushort)((u + 0x7fffu + ((u >> 16) & 1u)) >> 16);   // RNE f32->bf16
}
DEV ushort f2bn(float f){
  return __builtin_bit_cast(ushort, __float2bfloat16(f));
}

DEV void gload16(const void* g, void* l){
  __builtin_amdgcn_global_load_lds((const __attribute__((address_space(1))) void*)g,
                                   (__attribute__((address_space(3))) void*)l, 16, 0, 0);
}

#define SCALE_C 0.18033688f   // 0.125 * log2(e), folded into Q projections

// ---------------- fused f32->bf16 conversions + f32 bias concat ----------------
struct ConvArgs {
  const float* src[17];
  void*        dst[17];
  int blk_end[17];
  int nel[17];
  unsigned f32mask;
};

__global__ void __launch_bounds__(256) k_conv(ConvArgs a){
  int bi = blockIdx.x, seg = 0;
  while (bi >= a.blk_end[seg]) seg++;
  int b0 = seg ? a.blk_end[seg-1] : 0;
  long off = (long)(bi - b0)*2048 + (long)threadIdx.x*8;
  if (off >= a.nel[seg]) return;
  const float* s = a.src[seg] + off;
  f32x4 v0 = *(const f32x4*)s;
  f32x4 v1 = *(const f32x4*)(s+4);
  if ((a.f32mask >> seg) & 1u){
    float* d = (float*)a.dst[seg] + off;
    *(f32x4*)d = v0; *(f32x4*)(d+4) = v1;
  } else {
    ushort* d = (ushort*)a.dst[seg] + off;
    s16x8 o;
#pragma unroll
    for (int j = 0; j < 4; j++){ o[j] = (short)f2bu(v0[j]); o[4+j] = (short)f2bu(v1[j]); }
    *(s16x8*)d = o;
  }
}

// ---------------- 128x128 dbuf GEMM, bf16 out with scale (cross-Q), XCD-swizzled ----------------
__global__ void __launch_bounds__(256) k_gemm(const ushort* __restrict__ A, const ushort* __restrict__ W,
    const float* __restrict__ bias, ushort* __restrict__ Cb,
    int M, int N, int K, int lda, int ldb, float scale)
{
  __shared__ __align__(16) ushort lsA[2][128*64];
  __shared__ __align__(16) ushort lsB[2][128*64];
  const int t = threadIdx.x, w = t >> 6, u = t & 63, lr = u & 15, lk = u >> 4;
  const int gx = gridDim.x, nwg = gx * gridDim.y;
  const int id = blockIdx.y * gx + blockIdx.x;
  const int swz = (id & 7) * (nwg >> 3) + (id >> 3);     // bijective: nwg % 8 == 0
  const int n0 = (swz % gx) * 128, m0 = (swz / gx) * 128;
  const int wm = w >> 1, wn = w & 1;
  const int rA = t >> 3, c8 = (t & 7) * 8;
  const ushort* Ap = A + (size_t)(m0 + rA) * lda + c8;
  const ushort* Wp = W + (size_t)(n0 + rA) * ldb + c8;
  f32x4 acc[4][4] = {};
  const int nk = K >> 6;

  auto stage = [&](int k0, int buf){
#pragma unroll
    for (int j = 0; j < 4; j++){
      gload16(Ap + (size_t)j*32*lda + k0, &lsA[buf][0] + j*2048 + w*512);
      gload16(Wp + (size_t)j*32*ldb + k0, &lsB[buf][0] + j*2048 + w*512);
    }
  };
  stage(0, 0);
  for (int tk = 0; tk < nk; ++tk){
    __syncthreads();
    if (tk + 1 < nk) stage((tk + 1) << 6, (tk + 1) & 1);
    const ushort* La = &lsA[tk & 1][0];
    const ushort* Lb = &lsB[tk & 1][0];
#pragma unroll
    for (int ks = 0; ks < 2; ks++){
      s16x8 af[4], bfr[4];
#pragma unroll
      for (int i = 0; i < 4; i++) af[i]  = *(const s16x8*)(La + (wm*64 + i*16 + lr)*64 + ks*32 + lk*8);
#pragma unroll
      for (int i = 0; i < 4; i++) bfr[i] = *(const s16x8*)(Lb + (wn*64 + i*16 + lr)*64 + ks*32 + lk*8);
#pragma unroll
      for (int mi = 0; mi < 4; mi++)
#pragma unroll
        for (int ni = 0; ni < 4; ni++)
          acc[mi][ni] = __builtin_amdgcn_mfma_f32_16x16x32_bf16(af[mi], bfr[ni], acc[mi][ni], 0, 0, 0);
    }
  }

#pragma unroll
  for (int mi = 0; mi < 4; mi++){
#pragma unroll
    for (int ni = 0; ni < 4; ni++){
      const int row = m0 + wm*64 + mi*16 + lk*4;
      const int col = n0 + wn*64 + ni*16 + lr;
      const float bv = bias[col];
#pragma unroll
      for (int i = 0; i < 4; i++){
        float v = (acc[mi][ni][i] + bv) * scale;
        Cb[(size_t)(row + i) * N + col] = f2bn(v);
      }
    }
  }
}

// ---------------- 128x128 dbuf GEMM, split-K f32 out (wo1/wo2/FFN2), XCD-swizzled ----------------
__global__ void __launch_bounds__(256) k_gemmS(const ushort* __restrict__ A, const ushort* __restrict__ W,
    const float* __restrict__ bias, float* __restrict__ Cf,
    int M, int N, int Kext, int lda, int ldb, long long sstride)
{
  __shared__ __align__(16) ushort lsA[2][128*64];
  __shared__ __align__(16) ushort lsB[2][128*64];
  const int t = threadIdx.x, w = t >> 6, u = t & 63, lr = u & 15, lk = u >> 4;
  const int gx = gridDim.x, nwg = gx * gridDim.y;
  const int id = blockIdx.y * gx + blockIdx.x;
  const int swz = (id & 7) * (nwg >> 3) + (id >> 3);     // bijective: nwg % 8 == 0
  const int n0 = (swz % gx) * 128, m0 = (swz / gx) * 128;
  const int s = blockIdx.z;
  const int wm = w >> 1, wn = w & 1;
  const int rA = t >> 3, c8 = (t & 7) * 8;
  const ushort* Ap = A + (size_t)(m0 + rA) * lda + (size_t)s * Kext + c8;
  const ushort* Wp = W + (size_t)(n0 + rA) * ldb + (size_t)s * Kext + c8;
  if (s){ bias = nullptr; Cf += sstride; }
  f32x4 acc[4][4] = {};
  const int nk = Kext >> 6;

  auto stage = [&](int k0, int buf){
#pragma unroll
    for (int j = 0; j < 4; j++){
      gload16(Ap + (size_t)j*32*lda + k0, &lsA[buf][0] + j*2048 + w*512);
      gload16(Wp + (size_t)j*32*ldb + k0, &lsB[buf][0] + j*2048 + w*512);
    }
  };
  stage(0, 0);
  for (int tk = 0; tk < nk; ++tk){
    __syncthreads();
    if (tk + 1 < nk) stage((tk + 1) << 6, (tk + 1) & 1);
    const ushort* La = &lsA[tk & 1][0];
    const ushort* Lb = &lsB[tk & 1][0];
#pragma unroll
    for (int ks = 0; ks < 2; ks++){
      s16x8 af[4], bfr[4];
#pragma unroll
      for (int i = 0; i < 4; i++) af[i]  = *(const s16x8*)(La + (wm*64 + i*16 + lr)*64 + ks*32 + lk*8);
#pragma unroll
      for (int i = 0; i < 4; i++) bfr[i] = *(const s16x8*)(Lb + (wn*64 + i*16 + lr)*64 + ks*32 + lk*8);
#pragma unroll
      for (int mi = 0; mi < 4; mi++)
#pragma unroll
        for (int ni = 0; ni < 4; ni++)
          acc[mi][ni] = __builtin_amdgcn_mfma_f32_16x16x32_bf16(af[mi], bfr[ni], acc[mi][ni], 0, 0, 0);
    }
  }

#pragma unroll
  for (int mi = 0; mi < 4; mi++){
#pragma unroll
    for (int ni = 0; ni < 4; ni++){
      const int row = m0 + wm*64 + mi*16 + lk*4;
      const int col = n0 + wn*64 + ni*16 + lr;
      const float bv = bias ? bias[col] : 0.f;
#pragma unroll
      for (int i = 0; i < 4; i++)
        Cf[(size_t)(row + i) * N + col] = acc[mi][ni][i] + bv;
    }
  }
}

// ---------------- 256x256 8-phase GEMM (T2+T3+T4+T5) ----------------
// MODE 0: bf16 out, cols<scaleLim scaled; MODE 2: relu + bf16 out.
template<int MODE>
__global__ void __launch_bounds__(512, 1) k_gemm256(const ushort* __restrict__ A, const ushort* __restrict__ W,
    const float* __restrict__ bias, ushort* __restrict__ Cb,
    int N, int Ktot, int lda, int ldb, int scaleLim, float scale)
{
  __shared__ __align__(16) ushort lsA[2][256*64];
  __shared__ __align__(16) ushort lsB[2][256*64];
  const int t = threadIdx.x, w = t >> 6, u = t & 63, lr = u & 15, lk = u >> 4;
  const int gx = gridDim.x;
  const int nwg = gx * gridDim.y;
  const int id = blockIdx.y * gx + blockIdx.x;
  const int swz = (id & 7) * (nwg >> 3) + (id >> 3);      // bijective: nwg % 8 == 0
  const int n0 = (swz % gx) * 256, m0 = (swz / gx) * 256;
  const int wm = w >> 2, wn = w & 3;
  const int nt = Ktot >> 6;

  const int r0 = w*8 + (u >> 3), cc = u & 7;
  const int csw = 8 * (cc ^ (r0 & 7));
  const ushort* Ap = A + (size_t)(m0 + r0) * lda + csw;
  const ushort* Wp = W + (size_t)(n0 + r0) * ldb + csw;

  f32x4 acc[8][4] = {};
  const int swl = lr & 7;
  s16x8 afr[4], bfr[4];

#pragma unroll
  for (int j = 0; j < 4; j++){
    gload16(Ap + (size_t)(64*j)*lda, &lsA[0][0] + w*512 + j*4096);
    gload16(Wp + (size_t)(64*j)*ldb, &lsB[0][0] + w*512 + j*4096);
  }
  asm volatile("s_waitcnt vmcnt(0)" ::: "memory");
  __builtin_amdgcn_s_barrier();

  for (int tk = 0; tk < nt; ++tk){
    const char* La = (const char*)&lsA[tk & 1][0];
    const char* Lb = (const char*)&lsB[tk & 1][0];
    ushort* dA = &lsA[(tk & 1) ^ 1][0] + w*512;
    ushort* dB = &lsB[(tk & 1) ^ 1][0] + w*512;
    const bool pf = (tk + 1 < nt);
    const size_t k1 = (size_t)(tk + 1) << 6;

    // ---- phase 1 ----
#pragma unroll
    for (int i = 0; i < 4; i++)
      afr[i] = *(const s16x8*)(La + (wm*128 + i*16 + lr)*128 + ((lk ^ swl) * 16));
#pragma unroll
    for (int i = 0; i < 4; i++)
      bfr[i] = *(const s16x8*)(Lb + (wn*64 + i*16 + lr)*128 + ((lk ^ swl) * 16));
    if (pf){
      gload16(Ap + k1, dA);
      gload16(Wp + k1, dB);
      gload16(Ap + (size_t)64*lda + k1, dA + 4096);
      gload16(Wp + (size_t)64*ldb + k1, dB + 4096);
    }
    __builtin_amdgcn_s_barrier();
    asm volatile("s_waitcnt lgkmcnt(0)" ::: "memory");
    __builtin_amdgcn_s_setprio(1);
#pragma unroll
    for (int mi = 0; mi < 4; mi++)
#pragma unroll
      for (int ni = 0; ni < 4; ni++)
        acc[mi][ni] = __builtin_amdgcn_mfma_f32_16x16x32_bf16(afr[mi], bfr[ni], acc[mi][ni], 0, 0, 0);
    __builtin_amdgcn_s_setprio(0);
    __builtin_amdgcn_s_barrier();

    // ---- phase 2 ----
#pragma unroll
    for (int i = 0; i < 4; i++)
      afr[i] = *(const s16x8*)(La + (wm*128 + 64 + i*16 + lr)*128 + ((lk ^ swl) * 16));
    if (pf){
      gload16(Ap + (size_t)128*lda + k1, dA + 8192);
      gload16(Wp + (size_t)128*ldb + k1, dB + 8192);
      gload16(Ap + (size_t)192*lda + k1, dA + 12288);
      gload16(Wp + (size_t)192*ldb + k1, dB + 12288);
    }
    __builtin_amdgcn_s_barrier();
    asm volatile("s_waitcnt lgkmcnt(0)" ::: "memory");
    __builtin_amdgcn_s_setprio(1);
#pragma unroll
    for (int mi = 0; mi < 4; mi++)
#pragma unroll
      for (int ni = 0; ni < 4; ni++)
        acc[4+mi][ni] = __builtin_amdgcn_mfma_f32_16x16x32_bf16(afr[mi], bfr[ni], acc[4+mi][ni], 0, 0, 0);
    __builtin_amdgcn_s_setprio(0);
    __builtin_amdgcn_s_barrier();

    // ---- phase 3 ----
#pragma unroll
    for (int i = 0; i < 4; i++)
      afr[i] = *(const s16x8*)(La + (wm*128 + i*16 + lr)*128 + (((4 + lk) ^ swl) * 16));
#pragma unroll
    for (int i = 0; i < 4; i++)
      bfr[i] = *(const s16x8*)(Lb + (wn*64 + i*16 + lr)*128 + (((4 + lk) ^ swl) * 16));
    __builtin_amdgcn_s_barrier();
    asm volatile("s_waitcnt lgkmcnt(0)" ::: "memory");
    __builtin_amdgcn_s_setprio(1);
#pragma unroll
    for (int mi = 0; mi < 4; mi++)
#pragma unroll
      for (int ni = 0; ni < 4; ni++)
        acc[mi][ni] = __builtin_amdgcn_mfma_f32_16x16x32_bf16(afr[mi], bfr[ni], acc[mi][ni], 0, 0, 0);
    __builtin_amdgcn_s_setprio(0);
    __builtin_amdgcn_s_barrier();

    // ---- phase 4 ----
#pragma unroll
    for (int i = 0; i < 4; i++)
      afr[i] = *(const s16x8*)(La + (wm*128 + 64 + i*16 + lr)*128 + (((4 + lk) ^ swl) * 16));
    __builtin_amdgcn_s_barrier();
    asm volatile("s_waitcnt lgkmcnt(0)" ::: "memory");
    __builtin_amdgcn_s_setprio(1);
#pragma unroll
    for (int mi = 0; mi < 4; mi++)
#pragma unroll
      for (int ni = 0; ni < 4; ni++)
        acc[4+mi][ni] = __builtin_amdgcn_mfma_f32_16x16x32_bf16(afr[mi], bfr[ni], acc[4+mi][ni], 0, 0, 0);
    __builtin_amdgcn_s_setprio(0);
    asm volatile("s_waitcnt vmcnt(0)" ::: "memory");
    __builtin_amdgcn_s_barrier();
  }

#pragma unroll
  for (int mi = 0; mi < 8; mi++){
#pragma unroll
    for (int ni = 0; ni < 4; ni++){
      const int row = m0 + wm*128 + mi*16 + lk*4;
      const int col = n0 + wn*64 + ni*16 + lr;
      const float bv = bias[col];
#pragma unroll
      for (int i = 0; i < 4; i++){
        float v = acc[mi][ni][i] + bv;
        if (MODE == 2) v = fmaxf(v, 0.f);
        if (MODE == 0 && col < scaleLim) v *= scale;
        Cb[(size_t)(row + i) * N + col] = f2bn(v);
      }
    }
  }
}

// ---------------- V transpose: [B,S,(stride)] head-block -> Vt[B,H,64,S] ----------------
__global__ void __launch_bounds__(256) k_vt(const ushort* __restrict__ V, ushort* __restrict__ Vt,
                                            int stride, int S)
{
  __shared__ ushort tile[64][72];
  const int st = blockIdx.x*64, h = blockIdx.y, b = blockIdx.z;
  const int r = threadIdx.x >> 3, c8 = (threadIdx.x & 7)*8;
#pragma unroll
  for (int j = 0; j < 2; j++){
    int s = r + j*32;
    s16x8 v = *(const s16x8*)(V + (size_t)(b*S + st + s)*stride + h*64 + c8);
    *(s16x8*)&tile[s][c8] = v;
  }
  __syncthreads();
#pragma unroll
  for (int j = 0; j < 2; j++){
    int d = r + j*32;
    s16x8 o;
#pragma unroll
    for (int e = 0; e < 8; e++) o[e] = tile[c8+e][d];
    *(s16x8*)(Vt + ((size_t)((b*16 + h)*64 + d))*S + st + c8) = o;
  }
}

// ---------------- flash attention: 8 waves, QBLK=128, KVBLK=64 ----------------
// Q pre-scaled by 0.125*log2(e); m=0 softmax (exp2 direct).
// Row-sum via matrix pipe: lsum = mfma(P_frag, ONES) -> zero cross-lane reduction.
// CAUSAL: grid (32, 8): q-tiles {15-y, y}. cross: grid (32, 16).
template<bool CAUSAL>
__global__ void __launch_bounds__(512) k_attn(const ushort* __restrict__ Q, const ushort* __restrict__ Kg,
    const ushort* __restrict__ Vt, ushort* __restrict__ O, int sQ, int sK, int SQ, int SKV)
{
  __shared__ __align__(16) ushort Kl[2][64*64];
  __shared__ __align__(16) ushort Vl[2][64*64];
  __shared__ __align__(16) ushort Pl[8][16*64];
  const int t = threadIdx.x, w = t >> 6, u = t & 63, lr = u & 15, lk = u >> 4;
  const int hb = blockIdx.x;
  const int b = hb >> 4, h = hb & 15;
  const int srow = t >> 3, scol = t & 7;
  const size_t kvbase = (size_t)b * SKV;
  const size_t vtbase = (size_t)((b*16 + h)*64);
  char* Pc = (char*)&Pl[w][0];
  const int swzq = (lr & 7) << 4;

  s16x8 ONES;
#pragma unroll
  for (int j = 0; j < 8; j++) ONES[j] = (short)0x3F80;   // bf16 1.0

  auto stage = [&](int kt, int buf){
    gload16(Kg + (kvbase + kt*64 + srow)*sK + h*64 + 8*(scol ^ (srow & 7)), &Kl[buf][0] + w*512);
    gload16(Vt + (vtbase + srow)*SKV + kt*64 + 8*(scol ^ (srow & 7)), &Vl[buf][0] + w*512);
  };

  const int NREP = CAUSAL ? 2 : 1;
#pragma unroll 1
  for (int rep = 0; rep < NREP; rep++){
    const int qt = CAUSAL ? (rep ? (int)blockIdx.y : (int)(2*gridDim.y - 1 - blockIdx.y))
                          : (int)blockIdx.y;
    const int q0 = qt * 128;

    const ushort* qp = Q + (size_t)(b*SQ + q0 + w*16 + lr) * sQ + h*64 + lk*8;
    s16x8 qf0 = *(const s16x8*)qp;
    s16x8 qf1 = *(const s16x8*)(qp + 32);

    f32x4 oacc[4] = {};
    f32x4 lsum = {};
    const int nkt = CAUSAL ? (2*qt + 2) : (SKV >> 6);

    stage(0, 0);
    __syncthreads();

    for (int kt = 0; kt < nkt; kt++){
      const int buf = kt & 1;
      if (kt + 1 < nkt) stage(kt + 1, buf ^ 1);
      char* Kc = (char*)&Kl[buf][0];
      char* Vc = (char*)&Vl[buf][0];

      // S^T = K @ Q : lane holds S[q=lr][key = 16ni + 4lk + i] (already *0.125*log2e)
      f32x4 sacc[4] = {};
      __builtin_amdgcn_s_setprio(1);
#pragma unroll
      for (int ks = 0; ks < 2; ks++){
        s16x8 qf = ks ? qf1 : qf0;
#pragma unroll
        for (int ni = 0; ni < 4; ni++){
          int key = ni*16 + lr;
          s16x8 kf = *(const s16x8*)(Kc + key*128 + ((ks*64 + lk*16) ^ ((key & 7) << 4)));
          sacc[ni] = __builtin_amdgcn_mfma_f32_16x16x32_bf16(kf, qf, sacc[ni], 0, 0, 0);
        }
      }
      __builtin_amdgcn_s_setprio(0);
      if (CAUSAL && kt >= 2*qt){
        const int koff = kt*64 - q0;
#pragma unroll
        for (int ni = 0; ni < 4; ni++)
#pragma unroll
          for (int i = 0; i < 4; i++)
            if (koff + 16*ni + lk*4 + i > w*16 + lr) sacc[ni][i] = -1e30f;
      }

#pragma unroll
      for (int ni = 0; ni < 4; ni++)
#pragma unroll
        for (int i = 0; i < 4; i++) sacc[ni][i] = __builtin_exp2f(sacc[ni][i]);

#pragma unroll
      for (int ni = 0; ni < 4; ni++){
        s16x4 pk;
#pragma unroll
        for (int i = 0; i < 4; i++) pk[i] = (short)f2bn(sacc[ni][i]);
        *(s16x4*)(Pc + lr*128 + ((32*ni + 8*lk) ^ swzq)) = pk;
      }

      __builtin_amdgcn_s_setprio(1);
#pragma unroll
      for (int ks = 0; ks < 2; ks++){
        s16x8 pf = *(const s16x8*)(Pc + lr*128 + ((ks*64 + lk*16) ^ swzq));
        lsum = __builtin_amdgcn_mfma_f32_16x16x32_bf16(pf, ONES, lsum, 0, 0, 0);
#pragma unroll
        for (int ni = 0; ni < 4; ni++){
          int d = ni*16 + lr;
          s16x8 vf = *(const s16x8*)(Vc + d*128 + ((ks*64 + lk*16) ^ ((d & 7) << 4)));
          oacc[ni] = __builtin_amdgcn_mfma_f32_16x16x32_bf16(pf, vf, oacc[ni], 0, 0, 0);
        }
      }
      __builtin_amdgcn_s_setprio(0);
      __syncthreads();
    }

    // lsum[i] holds the denominator for row q = q0 + w*16 + lk*4 + i
    float invl[4];
#pragma unroll
    for (int i = 0; i < 4; i++) invl[i] = 1.f / lsum[i];
#pragma unroll
    for (int ni = 0; ni < 4; ni++)
#pragma unroll
      for (int i = 0; i < 4; i++)
        O[(size_t)(b*SQ + q0 + w*16 + lk*4 + i)*1024 + h*64 + ni*16 + lr] = f2bn(oacc[ni][i] * invl[i]);
  }
}

// ---------------- residual + LayerNorm (E=1024), optional second partial ----------------
template<bool WB16>
__global__ void __launch_bounds__(256) k_ln(const float* __restrict__ R, const float* __restrict__ P,
    const float* __restrict__ P2, const float* __restrict__ G, const float* __restrict__ Bv,
    float* __restrict__ Of, ushort* __restrict__ Ob)
{
  const int row = blockIdx.x, t = threadIdx.x, w = t >> 6, u = t & 63;
  const size_t base = (size_t)row * 1024 + t * 4;
  f32x4 r = *(const f32x4*)(R + base);
  f32x4 p = *(const f32x4*)(P + base);
  f32x4 v = r + p;
  if (P2){ f32x4 p2 = *(const f32x4*)(P2 + base); v += p2; }
  float s = 0.f, q = 0.f;
#pragma unroll
  for (int j = 0; j < 4; j++){ s += v[j]; q += v[j]*v[j]; }
#pragma unroll
  for (int md = 1; md < 64; md <<= 1){ s += __shfl_xor(s, md); q += __shfl_xor(q, md); }
  __shared__ float ps[4], pq[4];
  if (u == 0){ ps[w] = s; pq[w] = q; }
  __syncthreads();
  s = ps[0] + ps[1] + ps[2] + ps[3];
  q = pq[0] + pq[1] + pq[2] + pq[3];
  const float mean = s * (1.f/1024.f);
  const float var  = q * (1.f/1024.f) - mean*mean;
  const float rstd = rsqrtf(var + 1e-5f);
  f32x4 g4 = *(const f32x4*)(G  + t*4);
  f32x4 b4 = *(const f32x4*)(Bv + t*4);
  f32x4 o;
#pragma unroll
  for (int j = 0; j < 4; j++) o[j] = (v[j] - mean) * rstd * g4[j] + b4[j];
  *(f32x4*)(Of + base) = o;
  if (WB16){
    s16x4 ob;
#pragma unroll
    for (int j = 0; j < 4; j++) ob[j] = (short)f2bn(o[j]);
    *(s16x4*)(Ob + base) = ob;
  }
}

// ---------------- launch ----------------
extern "C" void kernel_launch(void* const* d_in, const int* in_sizes, int n_in,
                              void* d_out, int out_size, void* d_ws, size_t ws_size,
                              hipStream_t stream)
{
  const float* x   = (const float*)d_in[0];
  const float* enc = (const float*)d_in[1];
  const float* aw[8]; const float* ab[8];
  for (int i = 0; i < 8; i++){ aw[i] = (const float*)d_in[2 + 2*i]; ab[i] = (const float*)d_in[3 + 2*i]; }
  const float* w1 = (const float*)d_in[18]; const float* b1 = (const float*)d_in[19];
  const float* w2 = (const float*)d_in[20]; const float* b2 = (const float*)d_in[21];
  const float* lg[3] = {(const float*)d_in[22], (const float*)d_in[24], (const float*)d_in[26]};
  const float* lb[3] = {(const float*)d_in[23], (const float*)d_in[25], (const float*)d_in[27]};
  float* out = (float*)d_out;

  const size_t MB = 1024ull * 1024ull;
  if (ws_size < 129 * MB) return;
  char* ws = (char*)d_ws;
  ushort* wqkv = (ushort*)(ws + 0*MB);
  ushort* wcq  = (ushort*)(ws + 6*MB);
  ushort* wkv  = (ushort*)(ws + 8*MB);
  ushort* wo1w = (ushort*)(ws + 12*MB);
  ushort* wo2w = (ushort*)(ws + 14*MB);
  ushort* w1b  = (ushort*)(ws + 16*MB);
  ushort* w2b  = (ushort*)(ws + 24*MB);
  ushort* xb   = (ushort*)(ws + 32*MB);     // dead after QKV
  ushort* encb = (ushort*)(ws + 40*MB);     // dead after cKV
  ushort* attb = (ushort*)(ws + 48*MB);
  float*  proj = (float*)(ws + 56*MB);
  float*  x1f  = (float*)(ws + 72*MB);
  ushort* xab  = (ushort*)(ws + 88*MB);
  // phase region [96MB,128MB)
  ushort* QKVb    = (ushort*)(ws + 96*MB);
  ushort* Vt1     = (ushort*)(ws + 120*MB);
  ushort* crossQb = (ushort*)(ws + 96*MB);
  ushort* encKVb  = (ushort*)(ws + 104*MB);
  ushort* Vt2     = (ushort*)(ws + 120*MB);
  ushort* hb      = (ushort*)(ws + 96*MB);   // FFN1 out (live through FFN2)
  float*  pWO     = (float*)(ws + 96*MB);    // wo split-K partial (phase region dead then)
  float*  pFF     = (float*)(ws + 32*MB);    // FFN2 partial (xb/encb dead)
  float*  bqkv = (float*)(ws + 128*MB);
  float*  bkv  = (float*)(ws + 128*MB + 16384);

  const long long ssWO  = ((long long)(96 - 56) * (long long)MB) / 4;
  const long long ssFFN = ((long long)(32 - 56) * (long long)MB) / 4;   // negative offset

  // ---- fused conversions ----
  ConvArgs ca;
  const float* srcs[17] = { x, enc, aw[0], aw[1], aw[2], aw[3], aw[4], aw[5], aw[6], aw[7],
                            w1, w2, ab[0], ab[1], ab[2], ab[5], ab[6] };
  void* dsts[17] = { xb, encb, wqkv, wqkv + 1048576, wqkv + 2097152, wo1w, wcq, wkv, wkv + 1048576, wo2w,
                     w1b, w2b, bqkv, bqkv + 1024, bqkv + 2048, bkv, bkv + 1024 };
  int nels[17] = { 4194304, 4194304, 1048576, 1048576, 1048576, 1048576, 1048576, 1048576, 1048576, 1048576,
                   4194304, 4194304, 1024, 1024, 1024, 1024, 1024 };
  int acc_blk = 0;
  for (int i = 0; i < 17; i++){
    ca.src[i] = srcs[i]; ca.dst[i] = dsts[i]; ca.nel[i] = nels[i];
    acc_blk += (nels[i] + 2047) / 2048;
    ca.blk_end[i] = acc_blk;
  }
  ca.f32mask = 0x1F000u;
  k_conv<<<acc_blk, 256, 0, stream>>>(ca);

  // ---- self-attention block ----
  k_gemm256<0><<<dim3(12,16), 512, 0, stream>>>(xb, wqkv, bqkv, QKVb, 3072, 1024, 1024, 1024, 1024, SCALE_C);
  k_vt<<<dim3(32,16,2), 256, 0, stream>>>(QKVb + 2048, Vt1, 3072, 2048);
  k_attn<true><<<dim3(32,8), 512, 0, stream>>>(QKVb, QKVb + 1024, Vt1, attb, 3072, 3072, 2048, 2048);
  k_gemmS<<<dim3(8,32,2), 256, 0, stream>>>(attb, wo1w, ab[3], proj, 4096, 1024, 512, 1024, 1024, ssWO);
  k_ln<true><<<4096, 256, 0, stream>>>(x, proj, pWO, lg[0], lb[0], x1f, xab);

  // ---- cross-attention block ----
  k_gemm<<<dim3(8,32), 256, 0, stream>>>(xab, wcq, ab[4], crossQb, 4096, 1024, 1024, 1024, 1024, SCALE_C);
  k_gemm256<0><<<dim3(8,16), 512, 0, stream>>>(encb, wkv, bkv, encKVb, 2048, 1024, 1024, 1024, 0, 1.f);
  k_vt<<<dim3(32,16,2), 256, 0, stream>>>(encKVb + 1024, Vt2, 2048, 2048);
  k_attn<false><<<dim3(32,16), 512, 0, stream>>>(crossQb, encKVb, Vt2, attb, 1024, 2048, 2048, 2048);
  k_gemmS<<<dim3(8,32,2), 256, 0, stream>>>(attb, wo2w, ab[7], proj, 4096, 1024, 512, 1024, 1024, ssWO);
  k_ln<true><<<4096, 256, 0, stream>>>(x1f, proj, pWO, lg[1], lb[1], x1f, xab);   // x1f -> x2 in place

  // ---- FFN block ----
  k_gemm256<2><<<dim3(16,16), 512, 0, stream>>>(xab, w1b, b1, hb, 4096, 1024, 1024, 1024, 0, 1.f);
  k_gemmS<<<dim3(8,32,2), 256, 0, stream>>>(hb, w2b, b2, proj, 4096, 1024, 2048, 4096, 4096, ssFFN);
  k_ln<false><<<4096, 256, 0, stream>>>(x1f, proj, pFF, lg[2], lb[2], out, nullptr);
}

// Round 15
// 386.295 us; speedup vs baseline: 1.0831x; 1.0043x over previous
//
#include <hip/hip_runtime.h>
#include <hip/hip_bf16.h>
#include <stdint.h>

typedef __attribute__((ext_vector_type(8)))  short s16x8;
typedef __attribute__((ext_vector_type(4)))  short s16x4;
typedef __attribute__((ext_vector_type(4)))  float f32x4;

#define DEV static __device__ __forceinline__

DEV ushort f2bu(float f){
  unsigned u = __builtin_bit_cast(unsigned, f);
  return (ushort)((u + 0x7fffu + ((u >> 16) & 1u)) >> 16);   // RNE f32->bf16
}
DEV ushort f2bn(float f){
  return __builtin_bit_cast(ushort, __float2bfloat16(f));
}

DEV void gload16(const void* g, void* l){
  __builtin_amdgcn_global_load_lds((const __attribute__((address_space(1))) void*)g,
                                   (__attribute__((address_space(3))) void*)l, 16, 0, 0);
}

#define SCALE_C 0.18033688f   // 0.125 * log2(e), folded into Q projections

// ---------------- fused f32->bf16 conversions + f32 bias concat ----------------
struct ConvArgs {
  const float* src[17];
  void*        dst[17];
  int blk_end[17];
  int nel[17];
  unsigned f32mask;
};

__global__ void __launch_bounds__(256) k_conv(ConvArgs a){
  int bi = blockIdx.x, seg = 0;
  while (bi >= a.blk_end[seg]) seg++;
  int b0 = seg ? a.blk_end[seg-1] : 0;
  long off = (long)(bi - b0)*2048 + (long)threadIdx.x*8;
  if (off >= a.nel[seg]) return;
  const float* s = a.src[seg] + off;
  f32x4 v0 = *(const f32x4*)s;
  f32x4 v1 = *(const f32x4*)(s+4);
  if ((a.f32mask >> seg) & 1u){
    float* d = (float*)a.dst[seg] + off;
    *(f32x4*)d = v0; *(f32x4*)(d+4) = v1;
  } else {
    ushort* d = (ushort*)a.dst[seg] + off;
    s16x8 o;
#pragma unroll
    for (int j = 0; j < 4; j++){ o[j] = (short)f2bu(v0[j]); o[4+j] = (short)f2bu(v1[j]); }
    *(s16x8*)d = o;
  }
}

// ---------------- 128x128 dbuf GEMM, bf16 out with scale (cross-Q), XCD-swizzled ----------------
__global__ void __launch_bounds__(256) k_gemm(const ushort* __restrict__ A, const ushort* __restrict__ W,
    const float* __restrict__ bias, ushort* __restrict__ Cb,
    int M, int N, int K, int lda, int ldb, float scale)
{
  __shared__ __align__(16) ushort lsA[2][128*64];
  __shared__ __align__(16) ushort lsB[2][128*64];
  const int t = threadIdx.x, w = t >> 6, u = t & 63, lr = u & 15, lk = u >> 4;
  const int gx = gridDim.x, nwg = gx * gridDim.y;
  const int id = blockIdx.y * gx + blockIdx.x;
  const int swz = (id & 7) * (nwg >> 3) + (id >> 3);     // bijective: nwg % 8 == 0
  const int n0 = (swz % gx) * 128, m0 = (swz / gx) * 128;
  const int wm = w >> 1, wn = w & 1;
  const int rA = t >> 3, c8 = (t & 7) * 8;
  const ushort* Ap = A + (size_t)(m0 + rA) * lda + c8;
  const ushort* Wp = W + (size_t)(n0 + rA) * ldb + c8;
  f32x4 acc[4][4] = {};
  const int nk = K >> 6;

  auto stage = [&](int k0, int buf){
#pragma unroll
    for (int j = 0; j < 4; j++){
      gload16(Ap + (size_t)j*32*lda + k0, &lsA[buf][0] + j*2048 + w*512);
      gload16(Wp + (size_t)j*32*ldb + k0, &lsB[buf][0] + j*2048 + w*512);
    }
  };
  stage(0, 0);
  for (int tk = 0; tk < nk; ++tk){
    __syncthreads();
    if (tk + 1 < nk) stage((tk + 1) << 6, (tk + 1) & 1);
    const ushort* La = &lsA[tk & 1][0];
    const ushort* Lb = &lsB[tk & 1][0];
#pragma unroll
    for (int ks = 0; ks < 2; ks++){
      s16x8 af[4], bfr[4];
#pragma unroll
      for (int i = 0; i < 4; i++) af[i]  = *(const s16x8*)(La + (wm*64 + i*16 + lr)*64 + ks*32 + lk*8);
#pragma unroll
      for (int i = 0; i < 4; i++) bfr[i] = *(const s16x8*)(Lb + (wn*64 + i*16 + lr)*64 + ks*32 + lk*8);
#pragma unroll
      for (int mi = 0; mi < 4; mi++)
#pragma unroll
        for (int ni = 0; ni < 4; ni++)
          acc[mi][ni] = __builtin_amdgcn_mfma_f32_16x16x32_bf16(af[mi], bfr[ni], acc[mi][ni], 0, 0, 0);
    }
  }

#pragma unroll
  for (int mi = 0; mi < 4; mi++){
#pragma unroll
    for (int ni = 0; ni < 4; ni++){
      const int row = m0 + wm*64 + mi*16 + lk*4;
      const int col = n0 + wn*64 + ni*16 + lr;
      const float bv = bias[col];
#pragma unroll
      for (int i = 0; i < 4; i++){
        float v = (acc[mi][ni][i] + bv) * scale;
        Cb[(size_t)(row + i) * N + col] = f2bn(v);
      }
    }
  }
}

// ---------------- 128x128 dbuf GEMM, split-K f32 out (wo1/wo2/FFN2), XCD-swizzled ----------------
__global__ void __launch_bounds__(256) k_gemmS(const ushort* __restrict__ A, const ushort* __restrict__ W,
    const float* __restrict__ bias, float* __restrict__ Cf,
    int M, int N, int Kext, int lda, int ldb, long long sstride)
{
  __shared__ __align__(16) ushort lsA[2][128*64];
  __shared__ __align__(16) ushort lsB[2][128*64];
  const int t = threadIdx.x, w = t >> 6, u = t & 63, lr = u & 15, lk = u >> 4;
  const int gx = gridDim.x, nwg = gx * gridDim.y;
  const int id = blockIdx.y * gx + blockIdx.x;
  const int swz = (id & 7) * (nwg >> 3) + (id >> 3);     // bijective: nwg % 8 == 0
  const int n0 = (swz % gx) * 128, m0 = (swz / gx) * 128;
  const int s = blockIdx.z;
  const int wm = w >> 1, wn = w & 1;
  const int rA = t >> 3, c8 = (t & 7) * 8;
  const ushort* Ap = A + (size_t)(m0 + rA) * lda + (size_t)s * Kext + c8;
  const ushort* Wp = W + (size_t)(n0 + rA) * ldb + (size_t)s * Kext + c8;
  if (s){ bias = nullptr; Cf += sstride; }
  f32x4 acc[4][4] = {};
  const int nk = Kext >> 6;

  auto stage = [&](int k0, int buf){
#pragma unroll
    for (int j = 0; j < 4; j++){
      gload16(Ap + (size_t)j*32*lda + k0, &lsA[buf][0] + j*2048 + w*512);
      gload16(Wp + (size_t)j*32*ldb + k0, &lsB[buf][0] + j*2048 + w*512);
    }
  };
  stage(0, 0);
  for (int tk = 0; tk < nk; ++tk){
    __syncthreads();
    if (tk + 1 < nk) stage((tk + 1) << 6, (tk + 1) & 1);
    const ushort* La = &lsA[tk & 1][0];
    const ushort* Lb = &lsB[tk & 1][0];
#pragma unroll
    for (int ks = 0; ks < 2; ks++){
      s16x8 af[4], bfr[4];
#pragma unroll
      for (int i = 0; i < 4; i++) af[i]  = *(const s16x8*)(La + (wm*64 + i*16 + lr)*64 + ks*32 + lk*8);
#pragma unroll
      for (int i = 0; i < 4; i++) bfr[i] = *(const s16x8*)(Lb + (wn*64 + i*16 + lr)*64 + ks*32 + lk*8);
#pragma unroll
      for (int mi = 0; mi < 4; mi++)
#pragma unroll
        for (int ni = 0; ni < 4; ni++)
          acc[mi][ni] = __builtin_amdgcn_mfma_f32_16x16x32_bf16(af[mi], bfr[ni], acc[mi][ni], 0, 0, 0);
    }
  }

#pragma unroll
  for (int mi = 0; mi < 4; mi++){
#pragma unroll
    for (int ni = 0; ni < 4; ni++){
      const int row = m0 + wm*64 + mi*16 + lk*4;
      const int col = n0 + wn*64 + ni*16 + lr;
      const float bv = bias ? bias[col] : 0.f;
#pragma unroll
      for (int i = 0; i < 4; i++)
        Cf[(size_t)(row + i) * N + col] = acc[mi][ni][i] + bv;
    }
  }
}

// ---------------- 256x256 8-phase GEMM (T2+T3+T4+T5) ----------------
// MODE 0: bf16 out, cols<scaleLim scaled; MODE 2: relu + bf16 out.
// VT: cols >= vstart are written TRANSPOSED to vt[b][h][64][2048] (V^T fused epilogue).
template<int MODE, bool VT>
__global__ void __launch_bounds__(512, 1) k_gemm256(const ushort* __restrict__ A, const ushort* __restrict__ W,
    const float* __restrict__ bias, ushort* __restrict__ Cb,
    int N, int Ktot, int lda, int ldb, int scaleLim, float scale,
    ushort* __restrict__ vt, int vstart)
{
  __shared__ __align__(16) ushort lsA[2][256*64];
  __shared__ __align__(16) ushort lsB[2][256*64];
  const int t = threadIdx.x, w = t >> 6, u = t & 63, lr = u & 15, lk = u >> 4;
  const int gx = gridDim.x;
  const int nwg = gx * gridDim.y;
  const int id = blockIdx.y * gx + blockIdx.x;
  const int swz = (id & 7) * (nwg >> 3) + (id >> 3);      // bijective: nwg % 8 == 0
  const int n0 = (swz % gx) * 256, m0 = (swz / gx) * 256;
  const int wm = w >> 2, wn = w & 3;
  const int nt = Ktot >> 6;

  const int r0 = w*8 + (u >> 3), cc = u & 7;
  const int csw = 8 * (cc ^ (r0 & 7));
  const ushort* Ap = A + (size_t)(m0 + r0) * lda + csw;
  const ushort* Wp = W + (size_t)(n0 + r0) * ldb + csw;

  f32x4 acc[8][4] = {};
  const int swl = lr & 7;
  s16x8 afr[4], bfr[4];

#pragma unroll
  for (int j = 0; j < 4; j++){
    gload16(Ap + (size_t)(64*j)*lda, &lsA[0][0] + w*512 + j*4096);
    gload16(Wp + (size_t)(64*j)*ldb, &lsB[0][0] + w*512 + j*4096);
  }
  asm volatile("s_waitcnt vmcnt(0)" ::: "memory");
  __builtin_amdgcn_s_barrier();

  for (int tk = 0; tk < nt; ++tk){
    const char* La = (const char*)&lsA[tk & 1][0];
    const char* Lb = (const char*)&lsB[tk & 1][0];
    ushort* dA = &lsA[(tk & 1) ^ 1][0] + w*512;
    ushort* dB = &lsB[(tk & 1) ^ 1][0] + w*512;
    const bool pf = (tk + 1 < nt);
    const size_t k1 = (size_t)(tk + 1) << 6;

    // ---- phase 1 ----
#pragma unroll
    for (int i = 0; i < 4; i++)
      afr[i] = *(const s16x8*)(La + (wm*128 + i*16 + lr)*128 + ((lk ^ swl) * 16));
#pragma unroll
    for (int i = 0; i < 4; i++)
      bfr[i] = *(const s16x8*)(Lb + (wn*64 + i*16 + lr)*128 + ((lk ^ swl) * 16));
    if (pf){
      gload16(Ap + k1, dA);
      gload16(Wp + k1, dB);
      gload16(Ap + (size_t)64*lda + k1, dA + 4096);
      gload16(Wp + (size_t)64*ldb + k1, dB + 4096);
    }
    __builtin_amdgcn_s_barrier();
    asm volatile("s_waitcnt lgkmcnt(0)" ::: "memory");
    __builtin_amdgcn_s_setprio(1);
#pragma unroll
    for (int mi = 0; mi < 4; mi++)
#pragma unroll
      for (int ni = 0; ni < 4; ni++)
        acc[mi][ni] = __builtin_amdgcn_mfma_f32_16x16x32_bf16(afr[mi], bfr[ni], acc[mi][ni], 0, 0, 0);
    __builtin_amdgcn_s_setprio(0);
    __builtin_amdgcn_s_barrier();

    // ---- phase 2 ----
#pragma unroll
    for (int i = 0; i < 4; i++)
      afr[i] = *(const s16x8*)(La + (wm*128 + 64 + i*16 + lr)*128 + ((lk ^ swl) * 16));
    if (pf){
      gload16(Ap + (size_t)128*lda + k1, dA + 8192);
      gload16(Wp + (size_t)128*ldb + k1, dB + 8192);
      gload16(Ap + (size_t)192*lda + k1, dA + 12288);
      gload16(Wp + (size_t)192*ldb + k1, dB + 12288);
    }
    __builtin_amdgcn_s_barrier();
    asm volatile("s_waitcnt lgkmcnt(0)" ::: "memory");
    __builtin_amdgcn_s_setprio(1);
#pragma unroll
    for (int mi = 0; mi < 4; mi++)
#pragma unroll
      for (int ni = 0; ni < 4; ni++)
        acc[4+mi][ni] = __builtin_amdgcn_mfma_f32_16x16x32_bf16(afr[mi], bfr[ni], acc[4+mi][ni], 0, 0, 0);
    __builtin_amdgcn_s_setprio(0);
    __builtin_amdgcn_s_barrier();

    // ---- phase 3 ----
#pragma unroll
    for (int i = 0; i < 4; i++)
      afr[i] = *(const s16x8*)(La + (wm*128 + i*16 + lr)*128 + (((4 + lk) ^ swl) * 16));
#pragma unroll
    for (int i = 0; i < 4; i++)
      bfr[i] = *(const s16x8*)(Lb + (wn*64 + i*16 + lr)*128 + (((4 + lk) ^ swl) * 16));
    __builtin_amdgcn_s_barrier();
    asm volatile("s_waitcnt lgkmcnt(0)" ::: "memory");
    __builtin_amdgcn_s_setprio(1);
#pragma unroll
    for (int mi = 0; mi < 4; mi++)
#pragma unroll
      for (int ni = 0; ni < 4; ni++)
        acc[mi][ni] = __builtin_amdgcn_mfma_f32_16x16x32_bf16(afr[mi], bfr[ni], acc[mi][ni], 0, 0, 0);
    __builtin_amdgcn_s_setprio(0);
    __builtin_amdgcn_s_barrier();

    // ---- phase 4 ----
#pragma unroll
    for (int i = 0; i < 4; i++)
      afr[i] = *(const s16x8*)(La + (wm*128 + 64 + i*16 + lr)*128 + (((4 + lk) ^ swl) * 16));
    __builtin_amdgcn_s_barrier();
    asm volatile("s_waitcnt lgkmcnt(0)" ::: "memory");
    __builtin_amdgcn_s_setprio(1);
#pragma unroll
    for (int mi = 0; mi < 4; mi++)
#pragma unroll
      for (int ni = 0; ni < 4; ni++)
        acc[4+mi][ni] = __builtin_amdgcn_mfma_f32_16x16x32_bf16(afr[mi], bfr[ni], acc[4+mi][ni], 0, 0, 0);
    __builtin_amdgcn_s_setprio(0);
    asm volatile("s_waitcnt vmcnt(0)" ::: "memory");
    __builtin_amdgcn_s_barrier();
  }

#pragma unroll
  for (int mi = 0; mi < 8; mi++){
#pragma unroll
    for (int ni = 0; ni < 4; ni++){
      const int row = m0 + wm*128 + mi*16 + lk*4;
      const int col = n0 + wn*64 + ni*16 + lr;
      const float bv = bias[col];
      if (VT && col >= vstart){
        // transposed store into vt[b][h][64][2048]: 4 consecutive s = one 8B store
        const int vh = (col - vstart) >> 6, vd = (col - vstart) & 63;
        const int bb = row >> 11, ss = row & 2047;
        s16x4 o4;
#pragma unroll
        for (int i = 0; i < 4; i++) o4[i] = (short)f2bn(acc[mi][ni][i] + bv);
        *(s16x4*)(vt + ((size_t)((bb*16 + vh)*64 + vd))*2048 + ss) = o4;
      } else {
#pragma unroll
        for (int i = 0; i < 4; i++){
          float v = acc[mi][ni][i] + bv;
          if (MODE == 2) v = fmaxf(v, 0.f);
          if (MODE == 0 && col < scaleLim) v *= scale;
          Cb[(size_t)(row + i) * N + col] = f2bn(v);
        }
      }
    }
  }
}

// ---------------- flash attention: 8 waves, QBLK=128, KVBLK=64 ----------------
// Q pre-scaled by 0.125*log2(e); m=0 softmax (exp2 direct).
// Row-sum via matrix pipe: lsum = mfma(P_frag, ONES) -> zero cross-lane reduction.
// CAUSAL: grid (32, 8): q-tiles {15-y, y}. cross: grid (32, 16).
template<bool CAUSAL>
__global__ void __launch_bounds__(512) k_attn(const ushort* __restrict__ Q, const ushort* __restrict__ Kg,
    const ushort* __restrict__ Vt, ushort* __restrict__ O, int sQ, int sK, int SQ, int SKV)
{
  __shared__ __align__(16) ushort Kl[2][64*64];
  __shared__ __align__(16) ushort Vl[2][64*64];
  __shared__ __align__(16) ushort Pl[8][16*64];
  const int t = threadIdx.x, w = t >> 6, u = t & 63, lr = u & 15, lk = u >> 4;
  const int hb = blockIdx.x;
  const int b = hb >> 4, h = hb & 15;
  const int srow = t >> 3, scol = t & 7;
  const size_t kvbase = (size_t)b * SKV;
  const size_t vtbase = (size_t)((b*16 + h)*64);
  char* Pc = (char*)&Pl[w][0];
  const int swzq = (lr & 7) << 4;

  s16x8 ONES;
#pragma unroll
  for (int j = 0; j < 8; j++) ONES[j] = (short)0x3F80;   // bf16 1.0

  auto stage = [&](int kt, int buf){
    gload16(Kg + (kvbase + kt*64 + srow)*sK + h*64 + 8*(scol ^ (srow & 7)), &Kl[buf][0] + w*512);
    gload16(Vt + (vtbase + srow)*SKV + kt*64 + 8*(scol ^ (srow & 7)), &Vl[buf][0] + w*512);
  };

  const int NREP = CAUSAL ? 2 : 1;
#pragma unroll 1
  for (int rep = 0; rep < NREP; rep++){
    const int qt = CAUSAL ? (rep ? (int)blockIdx.y : (int)(2*gridDim.y - 1 - blockIdx.y))
                          : (int)blockIdx.y;
    const int q0 = qt * 128;

    const ushort* qp = Q + (size_t)(b*SQ + q0 + w*16 + lr) * sQ + h*64 + lk*8;
    s16x8 qf0 = *(const s16x8*)qp;
    s16x8 qf1 = *(const s16x8*)(qp + 32);

    f32x4 oacc[4] = {};
    f32x4 lsum = {};
    const int nkt = CAUSAL ? (2*qt + 2) : (SKV >> 6);

    stage(0, 0);
    __syncthreads();

    for (int kt = 0; kt < nkt; kt++){
      const int buf = kt & 1;
      if (kt + 1 < nkt) stage(kt + 1, buf ^ 1);
      char* Kc = (char*)&Kl[buf][0];
      char* Vc = (char*)&Vl[buf][0];

      // S^T = K @ Q : lane holds S[q=lr][key = 16ni + 4lk + i] (already *0.125*log2e)
      f32x4 sacc[4] = {};
      __builtin_amdgcn_s_setprio(1);
#pragma unroll
      for (int ks = 0; ks < 2; ks++){
        s16x8 qf = ks ? qf1 : qf0;
#pragma unroll
        for (int ni = 0; ni < 4; ni++){
          int key = ni*16 + lr;
          s16x8 kf = *(const s16x8*)(Kc + key*128 + ((ks*64 + lk*16) ^ ((key & 7) << 4)));
          sacc[ni] = __builtin_amdgcn_mfma_f32_16x16x32_bf16(kf, qf, sacc[ni], 0, 0, 0);
        }
      }
      __builtin_amdgcn_s_setprio(0);
      if (CAUSAL && kt >= 2*qt){
        const int koff = kt*64 - q0;
#pragma unroll
        for (int ni = 0; ni < 4; ni++)
#pragma unroll
          for (int i = 0; i < 4; i++)
            if (koff + 16*ni + lk*4 + i > w*16 + lr) sacc[ni][i] = -1e30f;
      }

#pragma unroll
      for (int ni = 0; ni < 4; ni++)
#pragma unroll
        for (int i = 0; i < 4; i++) sacc[ni][i] = __builtin_exp2f(sacc[ni][i]);

#pragma unroll
      for (int ni = 0; ni < 4; ni++){
        s16x4 pk;
#pragma unroll
        for (int i = 0; i < 4; i++) pk[i] = (short)f2bn(sacc[ni][i]);
        *(s16x4*)(Pc + lr*128 + ((32*ni + 8*lk) ^ swzq)) = pk;
      }

      __builtin_amdgcn_s_setprio(1);
#pragma unroll
      for (int ks = 0; ks < 2; ks++){
        s16x8 pf = *(const s16x8*)(Pc + lr*128 + ((ks*64 + lk*16) ^ swzq));
        lsum = __builtin_amdgcn_mfma_f32_16x16x32_bf16(pf, ONES, lsum, 0, 0, 0);
#pragma unroll
        for (int ni = 0; ni < 4; ni++){
          int d = ni*16 + lr;
          s16x8 vf = *(const s16x8*)(Vc + d*128 + ((ks*64 + lk*16) ^ ((d & 7) << 4)));
          oacc[ni] = __builtin_amdgcn_mfma_f32_16x16x32_bf16(pf, vf, oacc[ni], 0, 0, 0);
        }
      }
      __builtin_amdgcn_s_setprio(0);
      __syncthreads();
    }

    // lsum[i] holds the denominator for row q = q0 + w*16 + lk*4 + i
    float invl[4];
#pragma unroll
    for (int i = 0; i < 4; i++) invl[i] = 1.f / lsum[i];
#pragma unroll
    for (int ni = 0; ni < 4; ni++)
#pragma unroll
      for (int i = 0; i < 4; i++)
        O[(size_t)(b*SQ + q0 + w*16 + lk*4 + i)*1024 + h*64 + ni*16 + lr] = f2bn(oacc[ni][i] * invl[i]);
  }
}

// ---------------- residual + LayerNorm (E=1024), optional second partial ----------------
template<bool WB16>
__global__ void __launch_bounds__(256) k_ln(const float* __restrict__ R, const float* __restrict__ P,
    const float* __restrict__ P2, const float* __restrict__ G, const float* __restrict__ Bv,
    float* __restrict__ Of, ushort* __restrict__ Ob)
{
  const int row = blockIdx.x, t = threadIdx.x, w = t >> 6, u = t & 63;
  const size_t base = (size_t)row * 1024 + t * 4;
  f32x4 r = *(const f32x4*)(R + base);
  f32x4 p = *(const f32x4*)(P + base);
  f32x4 v = r + p;
  if (P2){ f32x4 p2 = *(const f32x4*)(P2 + base); v += p2; }
  float s = 0.f, q = 0.f;
#pragma unroll
  for (int j = 0; j < 4; j++){ s += v[j]; q += v[j]*v[j]; }
#pragma unroll
  for (int md = 1; md < 64; md <<= 1){ s += __shfl_xor(s, md); q += __shfl_xor(q, md); }
  __shared__ float ps[4], pq[4];
  if (u == 0){ ps[w] = s; pq[w] = q; }
  __syncthreads();
  s = ps[0] + ps[1] + ps[2] + ps[3];
  q = pq[0] + pq[1] + pq[2] + pq[3];
  const float mean = s * (1.f/1024.f);
  const float var  = q * (1.f/1024.f) - mean*mean;
  const float rstd = rsqrtf(var + 1e-5f);
  f32x4 g4 = *(const f32x4*)(G  + t*4);
  f32x4 b4 = *(const f32x4*)(Bv + t*4);
  f32x4 o;
#pragma unroll
  for (int j = 0; j < 4; j++) o[j] = (v[j] - mean) * rstd * g4[j] + b4[j];
  *(f32x4*)(Of + base) = o;
  if (WB16){
    s16x4 ob;
#pragma unroll
    for (int j = 0; j < 4; j++) ob[j] = (short)f2bn(o[j]);
    *(s16x4*)(Ob + base) = ob;
  }
}

// ---------------- launch ----------------
extern "C" void kernel_launch(void* const* d_in, const int* in_sizes, int n_in,
                              void* d_out, int out_size, void* d_ws, size_t ws_size,
                              hipStream_t stream)
{
  const float* x   = (const float*)d_in[0];
  const float* enc = (const float*)d_in[1];
  const float* aw[8]; const float* ab[8];
  for (int i = 0; i < 8; i++){ aw[i] = (const float*)d_in[2 + 2*i]; ab[i] = (const float*)d_in[3 + 2*i]; }
  const float* w1 = (const float*)d_in[18]; const float* b1 = (const float*)d_in[19];
  const float* w2 = (const float*)d_in[20]; const float* b2 = (const float*)d_in[21];
  const float* lg[3] = {(const float*)d_in[22], (const float*)d_in[24], (const float*)d_in[26]};
  const float* lb[3] = {(const float*)d_in[23], (const float*)d_in[25], (const float*)d_in[27]};
  float* out = (float*)d_out;

  const size_t MB = 1024ull * 1024ull;
  if (ws_size < 129 * MB) return;
  char* ws = (char*)d_ws;
  ushort* wqkv = (ushort*)(ws + 0*MB);
  ushort* wcq  = (ushort*)(ws + 6*MB);
  ushort* wkv  = (ushort*)(ws + 8*MB);
  ushort* wo1w = (ushort*)(ws + 12*MB);
  ushort* wo2w = (ushort*)(ws + 14*MB);
  ushort* w1b  = (ushort*)(ws + 16*MB);
  ushort* w2b  = (ushort*)(ws + 24*MB);
  ushort* xb   = (ushort*)(ws + 32*MB);     // dead after QKV
  ushort* encb = (ushort*)(ws + 40*MB);     // dead after cKV
  ushort* attb = (ushort*)(ws + 48*MB);
  float*  proj = (float*)(ws + 56*MB);
  float*  x1f  = (float*)(ws + 72*MB);
  ushort* xab  = (ushort*)(ws + 88*MB);
  // phase region [96MB,128MB)
  ushort* QKVb    = (ushort*)(ws + 96*MB);
  ushort* Vt1     = (ushort*)(ws + 120*MB);
  ushort* crossQb = (ushort*)(ws + 96*MB);
  ushort* encKVb  = (ushort*)(ws + 104*MB);
  ushort* Vt2     = (ushort*)(ws + 120*MB);
  ushort* hb      = (ushort*)(ws + 96*MB);   // FFN1 out (live through FFN2)
  float*  pWO     = (float*)(ws + 96*MB);    // wo split-K partial (phase region dead then)
  float*  pFF     = (float*)(ws + 32*MB);    // FFN2 partial (xb/encb dead)
  float*  bqkv = (float*)(ws + 128*MB);
  float*  bkv  = (float*)(ws + 128*MB + 16384);

  const long long ssWO  = ((long long)(96 - 56) * (long long)MB) / 4;
  const long long ssFFN = ((long long)(32 - 56) * (long long)MB) / 4;   // negative offset

  // ---- fused conversions ----
  ConvArgs ca;
  const float* srcs[17] = { x, enc, aw[0], aw[1], aw[2], aw[3], aw[4], aw[5], aw[6], aw[7],
                            w1, w2, ab[0], ab[1], ab[2], ab[5], ab[6] };
  void* dsts[17] = { xb, encb, wqkv, wqkv + 1048576, wqkv + 2097152, wo1w, wcq, wkv, wkv + 1048576, wo2w,
                     w1b, w2b, bqkv, bqkv + 1024, bqkv + 2048, bkv, bkv + 1024 };
  int nels[17] = { 4194304, 4194304, 1048576, 1048576, 1048576, 1048576, 1048576, 1048576, 1048576, 1048576,
                   4194304, 4194304, 1024, 1024, 1024, 1024, 1024 };
  int acc_blk = 0;
  for (int i = 0; i < 17; i++){
    ca.src[i] = srcs[i]; ca.dst[i] = dsts[i]; ca.nel[i] = nels[i];
    acc_blk += (nels[i] + 2047) / 2048;
    ca.blk_end[i] = acc_blk;
  }
  ca.f32mask = 0x1F000u;
  k_conv<<<acc_blk, 256, 0, stream>>>(ca);

  // ---- self-attention block ----
  // QKV: Q cols scaled, V cols (>=2048) written transposed straight into Vt1
  k_gemm256<0,true><<<dim3(12,16), 512, 0, stream>>>(xb, wqkv, bqkv, QKVb, 3072, 1024, 1024, 1024,
                                                     1024, SCALE_C, Vt1, 2048);
  k_attn<true><<<dim3(32,8), 512, 0, stream>>>(QKVb, QKVb + 1024, Vt1, attb, 3072, 3072, 2048, 2048);
  k_gemmS<<<dim3(8,32,2), 256, 0, stream>>>(attb, wo1w, ab[3], proj, 4096, 1024, 512, 1024, 1024, ssWO);
  k_ln<true><<<4096, 256, 0, stream>>>(x, proj, pWO, lg[0], lb[0], x1f, xab);

  // ---- cross-attention block ----
  k_gemm<<<dim3(8,32), 256, 0, stream>>>(xab, wcq, ab[4], crossQb, 4096, 1024, 1024, 1024, 1024, SCALE_C);
  // cKV: V cols (>=1024) written transposed straight into Vt2
  k_gemm256<0,true><<<dim3(8,16), 512, 0, stream>>>(encb, wkv, bkv, encKVb, 2048, 1024, 1024, 1024,
                                                    0, 1.f, Vt2, 1024);
  k_attn<false><<<dim3(32,16), 512, 0, stream>>>(crossQb, encKVb, Vt2, attb, 1024, 2048, 2048, 2048);
  k_gemmS<<<dim3(8,32,2), 256, 0, stream>>>(attb, wo2w, ab[7], proj, 4096, 1024, 512, 1024, 1024, ssWO);
  k_ln<true><<<4096, 256, 0, stream>>>(x1f, proj, pWO, lg[1], lb[1], x1f, xab);   // x1f -> x2 in place

  // ---- FFN block ----
  k_gemm256<2,false><<<dim3(16,16), 512, 0, stream>>>(xab, w1b, b1, hb, 4096, 1024, 1024, 1024,
                                                      0, 1.f, nullptr, 1 << 30);
  k_gemmS<<<dim3(8,32,2), 256, 0, stream>>>(hb, w2b, b2, proj, 4096, 1024, 2048, 4096, 4096, ssFFN);
  k_ln<false><<<4096, 256, 0, stream>>>(x1f, proj, pFF, lg[2], lb[2], out, nullptr);
}

// Round 16
// 383.310 us; speedup vs baseline: 1.0915x; 1.0078x over previous
//
#include <hip/hip_runtime.h>
#include <hip/hip_bf16.h>
#include <stdint.h>

typedef __attribute__((ext_vector_type(8)))  short s16x8;
typedef __attribute__((ext_vector_type(4)))  short s16x4;
typedef __attribute__((ext_vector_type(4)))  float f32x4;

#define DEV static __device__ __forceinline__

DEV ushort f2bu(float f){
  unsigned u = __builtin_bit_cast(unsigned, f);
  return (ushort)((u + 0x7fffu + ((u >> 16) & 1u)) >> 16);   // RNE f32->bf16
}
DEV ushort f2bn(float f){
  return __builtin_bit_cast(ushort, __float2bfloat16(f));
}

DEV void gload16(const void* g, void* l){
  __builtin_amdgcn_global_load_lds((const __attribute__((address_space(1))) void*)g,
                                   (__attribute__((address_space(3))) void*)l, 16, 0, 0);
}

#define SCALE_C 0.18033688f   // 0.125 * log2(e), folded into Q projections

// ---------------- fused f32->bf16 conversions + f32 bias concat ----------------
struct ConvArgs {
  const float* src[17];
  void*        dst[17];
  int blk_end[17];
  int nel[17];
  unsigned f32mask;
};

__global__ void __launch_bounds__(256) k_conv(ConvArgs a){
  int bi = blockIdx.x, seg = 0;
  while (bi >= a.blk_end[seg]) seg++;
  int b0 = seg ? a.blk_end[seg-1] : 0;
  long off = (long)(bi - b0)*2048 + (long)threadIdx.x*8;
  if (off >= a.nel[seg]) return;
  const float* s = a.src[seg] + off;
  f32x4 v0 = *(const f32x4*)s;
  f32x4 v1 = *(const f32x4*)(s+4);
  if ((a.f32mask >> seg) & 1u){
    float* d = (float*)a.dst[seg] + off;
    *(f32x4*)d = v0; *(f32x4*)(d+4) = v1;
  } else {
    ushort* d = (ushort*)a.dst[seg] + off;
    s16x8 o;
#pragma unroll
    for (int j = 0; j < 4; j++){ o[j] = (short)f2bu(v0[j]); o[4+j] = (short)f2bu(v1[j]); }
    *(s16x8*)d = o;
  }
}

// ---------------- fused cQ + cKV 128x128 dbuf GEMM, per-segment XCD-aware tiling ----------------
// ids 0..255:   C0[4096,1024] = A0 @ W0^T * scale0  (XCD k: m-tiles [4k,4k+4), all 8 n)
// ids 256..767: C1[4096,2048] = A1 @ W1^T; cols >= 1024 stored transposed into vt[b][h][64][2048]
//               (XCD k: m-tiles [8*(k>>1)..+8), n-tiles [8*(k&1)..+8))
__global__ void __launch_bounds__(256) k_gemmB(
    const ushort* __restrict__ A0, const ushort* __restrict__ W0, const float* __restrict__ b0,
    ushort* __restrict__ C0,
    const ushort* __restrict__ A1, const ushort* __restrict__ W1, const float* __restrict__ b1,
    ushort* __restrict__ C1, ushort* __restrict__ vt, float scale0)
{
  __shared__ __align__(16) ushort lsA[2][128*64];
  __shared__ __align__(16) ushort lsB[2][128*64];
  const int t = threadIdx.x, w = t >> 6, u = t & 63, lr = u & 15, lk = u >> 4;
  const int bid = blockIdx.x;
  const ushort *A, *W; const float* bias; ushort* C;
  int N, m0, n0; float scale; bool seg1;
  if (bid < 256){
    const int k8 = bid & 7, j = bid >> 3;                 // j in 0..31
    m0 = (k8*4 + (j >> 3)) * 128;
    n0 = (j & 7) * 128;
    A = A0; W = W0; bias = b0; C = C0; N = 1024; scale = scale0; seg1 = false;
  } else {
    const int id2 = bid - 256;
    const int k8 = id2 & 7, j = id2 >> 3;                 // j in 0..63
    m0 = ((k8 >> 1)*8 + (j >> 3)) * 128;
    n0 = ((k8 & 1)*8 + (j & 7)) * 128;
    A = A1; W = W1; bias = b1; C = C1; N = 2048; scale = 1.f; seg1 = true;
  }
  const int wm = w >> 1, wn = w & 1;
  const int rA = t >> 3, c8 = (t & 7) * 8;
  const ushort* Ap = A + (size_t)(m0 + rA) * 1024 + c8;
  const ushort* Wp = W + (size_t)(n0 + rA) * 1024 + c8;
  f32x4 acc[4][4] = {};

  auto stage = [&](int k0, int buf){
#pragma unroll
    for (int j = 0; j < 4; j++){
      gload16(Ap + (size_t)j*32*1024 + k0, &lsA[buf][0] + j*2048 + w*512);
      gload16(Wp + (size_t)j*32*1024 + k0, &lsB[buf][0] + j*2048 + w*512);
    }
  };
  stage(0, 0);
  for (int tk = 0; tk < 16; ++tk){
    __syncthreads();
    if (tk + 1 < 16) stage((tk + 1) << 6, (tk + 1) & 1);
    const ushort* La = &lsA[tk & 1][0];
    const ushort* Lb = &lsB[tk & 1][0];
#pragma unroll
    for (int ks = 0; ks < 2; ks++){
      s16x8 af[4], bfr[4];
#pragma unroll
      for (int i = 0; i < 4; i++) af[i]  = *(const s16x8*)(La + (wm*64 + i*16 + lr)*64 + ks*32 + lk*8);
#pragma unroll
      for (int i = 0; i < 4; i++) bfr[i] = *(const s16x8*)(Lb + (wn*64 + i*16 + lr)*64 + ks*32 + lk*8);
#pragma unroll
      for (int mi = 0; mi < 4; mi++)
#pragma unroll
        for (int ni = 0; ni < 4; ni++)
          acc[mi][ni] = __builtin_amdgcn_mfma_f32_16x16x32_bf16(af[mi], bfr[ni], acc[mi][ni], 0, 0, 0);
    }
  }

#pragma unroll
  for (int mi = 0; mi < 4; mi++){
#pragma unroll
    for (int ni = 0; ni < 4; ni++){
      const int row = m0 + wm*64 + mi*16 + lk*4;
      const int col = n0 + wn*64 + ni*16 + lr;
      const float bv = bias[col];
      if (seg1 && col >= 1024){
        // V column -> transposed store into vt[b][h][64][2048]
        const int vh = (col - 1024) >> 6, vd = (col - 1024) & 63;
        const int bb = row >> 11, ss = row & 2047;
        s16x4 o4;
#pragma unroll
        for (int i = 0; i < 4; i++) o4[i] = (short)f2bn(acc[mi][ni][i] + bv);
        *(s16x4*)(vt + ((size_t)((bb*16 + vh)*64 + vd))*2048 + ss) = o4;
      } else {
#pragma unroll
        for (int i = 0; i < 4; i++){
          float v = (acc[mi][ni][i] + bv) * scale;
          C[(size_t)(row + i) * N + col] = f2bn(v);
        }
      }
    }
  }
}

// ---------------- 128x128 dbuf GEMM, split-K f32 out (wo1/wo2/FFN2), XCD-swizzled ----------------
__global__ void __launch_bounds__(256) k_gemmS(const ushort* __restrict__ A, const ushort* __restrict__ W,
    const float* __restrict__ bias, float* __restrict__ Cf,
    int M, int N, int Kext, int lda, int ldb, long long sstride)
{
  __shared__ __align__(16) ushort lsA[2][128*64];
  __shared__ __align__(16) ushort lsB[2][128*64];
  const int t = threadIdx.x, w = t >> 6, u = t & 63, lr = u & 15, lk = u >> 4;
  const int gx = gridDim.x, nwg = gx * gridDim.y;
  const int id = blockIdx.y * gx + blockIdx.x;
  const int swz = (id & 7) * (nwg >> 3) + (id >> 3);     // bijective: nwg % 8 == 0
  const int n0 = (swz % gx) * 128, m0 = (swz / gx) * 128;
  const int s = blockIdx.z;
  const int wm = w >> 1, wn = w & 1;
  const int rA = t >> 3, c8 = (t & 7) * 8;
  const ushort* Ap = A + (size_t)(m0 + rA) * lda + (size_t)s * Kext + c8;
  const ushort* Wp = W + (size_t)(n0 + rA) * ldb + (size_t)s * Kext + c8;
  if (s){ bias = nullptr; Cf += sstride; }
  f32x4 acc[4][4] = {};
  const int nk = Kext >> 6;

  auto stage = [&](int k0, int buf){
#pragma unroll
    for (int j = 0; j < 4; j++){
      gload16(Ap + (size_t)j*32*lda + k0, &lsA[buf][0] + j*2048 + w*512);
      gload16(Wp + (size_t)j*32*ldb + k0, &lsB[buf][0] + j*2048 + w*512);
    }
  };
  stage(0, 0);
  for (int tk = 0; tk < nk; ++tk){
    __syncthreads();
    if (tk + 1 < nk) stage((tk + 1) << 6, (tk + 1) & 1);
    const ushort* La = &lsA[tk & 1][0];
    const ushort* Lb = &lsB[tk & 1][0];
#pragma unroll
    for (int ks = 0; ks < 2; ks++){
      s16x8 af[4], bfr[4];
#pragma unroll
      for (int i = 0; i < 4; i++) af[i]  = *(const s16x8*)(La + (wm*64 + i*16 + lr)*64 + ks*32 + lk*8);
#pragma unroll
      for (int i = 0; i < 4; i++) bfr[i] = *(const s16x8*)(Lb + (wn*64 + i*16 + lr)*64 + ks*32 + lk*8);
#pragma unroll
      for (int mi = 0; mi < 4; mi++)
#pragma unroll
        for (int ni = 0; ni < 4; ni++)
          acc[mi][ni] = __builtin_amdgcn_mfma_f32_16x16x32_bf16(af[mi], bfr[ni], acc[mi][ni], 0, 0, 0);
    }
  }

#pragma unroll
  for (int mi = 0; mi < 4; mi++){
#pragma unroll
    for (int ni = 0; ni < 4; ni++){
      const int row = m0 + wm*64 + mi*16 + lk*4;
      const int col = n0 + wn*64 + ni*16 + lr;
      const float bv = bias ? bias[col] : 0.f;
#pragma unroll
      for (int i = 0; i < 4; i++)
        Cf[(size_t)(row + i) * N + col] = acc[mi][ni][i] + bv;
    }
  }
}

// ---------------- 256x256 8-phase GEMM (T2+T3+T4+T5) ----------------
// MODE 0: bf16 out, cols<scaleLim scaled; MODE 2: relu + bf16 out.
// VT: cols >= vstart are written TRANSPOSED to vt[b][h][64][2048] (V^T fused epilogue).
template<int MODE, bool VT>
__global__ void __launch_bounds__(512, 1) k_gemm256(const ushort* __restrict__ A, const ushort* __restrict__ W,
    const float* __restrict__ bias, ushort* __restrict__ Cb,
    int N, int Ktot, int lda, int ldb, int scaleLim, float scale,
    ushort* __restrict__ vt, int vstart)
{
  __shared__ __align__(16) ushort lsA[2][256*64];
  __shared__ __align__(16) ushort lsB[2][256*64];
  const int t = threadIdx.x, w = t >> 6, u = t & 63, lr = u & 15, lk = u >> 4;
  const int gx = gridDim.x;
  const int nwg = gx * gridDim.y;
  const int id = blockIdx.y * gx + blockIdx.x;
  const int swz = (id & 7) * (nwg >> 3) + (id >> 3);      // bijective: nwg % 8 == 0
  const int n0 = (swz % gx) * 256, m0 = (swz / gx) * 256;
  const int wm = w >> 2, wn = w & 3;
  const int nt = Ktot >> 6;

  const int r0 = w*8 + (u >> 3), cc = u & 7;
  const int csw = 8 * (cc ^ (r0 & 7));
  const ushort* Ap = A + (size_t)(m0 + r0) * lda + csw;
  const ushort* Wp = W + (size_t)(n0 + r0) * ldb + csw;

  f32x4 acc[8][4] = {};
  const int swl = lr & 7;
  s16x8 afr[4], bfr[4];

#pragma unroll
  for (int j = 0; j < 4; j++){
    gload16(Ap + (size_t)(64*j)*lda, &lsA[0][0] + w*512 + j*4096);
    gload16(Wp + (size_t)(64*j)*ldb, &lsB[0][0] + w*512 + j*4096);
  }
  asm volatile("s_waitcnt vmcnt(0)" ::: "memory");
  __builtin_amdgcn_s_barrier();

  for (int tk = 0; tk < nt; ++tk){
    const char* La = (const char*)&lsA[tk & 1][0];
    const char* Lb = (const char*)&lsB[tk & 1][0];
    ushort* dA = &lsA[(tk & 1) ^ 1][0] + w*512;
    ushort* dB = &lsB[(tk & 1) ^ 1][0] + w*512;
    const bool pf = (tk + 1 < nt);
    const size_t k1 = (size_t)(tk + 1) << 6;

    // ---- phase 1 ----
#pragma unroll
    for (int i = 0; i < 4; i++)
      afr[i] = *(const s16x8*)(La + (wm*128 + i*16 + lr)*128 + ((lk ^ swl) * 16));
#pragma unroll
    for (int i = 0; i < 4; i++)
      bfr[i] = *(const s16x8*)(Lb + (wn*64 + i*16 + lr)*128 + ((lk ^ swl) * 16));
    if (pf){
      gload16(Ap + k1, dA);
      gload16(Wp + k1, dB);
      gload16(Ap + (size_t)64*lda + k1, dA + 4096);
      gload16(Wp + (size_t)64*ldb + k1, dB + 4096);
    }
    __builtin_amdgcn_s_barrier();
    asm volatile("s_waitcnt lgkmcnt(0)" ::: "memory");
    __builtin_amdgcn_s_setprio(1);
#pragma unroll
    for (int mi = 0; mi < 4; mi++)
#pragma unroll
      for (int ni = 0; ni < 4; ni++)
        acc[mi][ni] = __builtin_amdgcn_mfma_f32_16x16x32_bf16(afr[mi], bfr[ni], acc[mi][ni], 0, 0, 0);
    __builtin_amdgcn_s_setprio(0);
    __builtin_amdgcn_s_barrier();

    // ---- phase 2 ----
#pragma unroll
    for (int i = 0; i < 4; i++)
      afr[i] = *(const s16x8*)(La + (wm*128 + 64 + i*16 + lr)*128 + ((lk ^ swl) * 16));
    if (pf){
      gload16(Ap + (size_t)128*lda + k1, dA + 8192);
      gload16(Wp + (size_t)128*ldb + k1, dB + 8192);
      gload16(Ap + (size_t)192*lda + k1, dA + 12288);
      gload16(Wp + (size_t)192*ldb + k1, dB + 12288);
    }
    __builtin_amdgcn_s_barrier();
    asm volatile("s_waitcnt lgkmcnt(0)" ::: "memory");
    __builtin_amdgcn_s_setprio(1);
#pragma unroll
    for (int mi = 0; mi < 4; mi++)
#pragma unroll
      for (int ni = 0; ni < 4; ni++)
        acc[4+mi][ni] = __builtin_amdgcn_mfma_f32_16x16x32_bf16(afr[mi], bfr[ni], acc[4+mi][ni], 0, 0, 0);
    __builtin_amdgcn_s_setprio(0);
    __builtin_amdgcn_s_barrier();

    // ---- phase 3 ----
#pragma unroll
    for (int i = 0; i < 4; i++)
      afr[i] = *(const s16x8*)(La + (wm*128 + i*16 + lr)*128 + (((4 + lk) ^ swl) * 16));
#pragma unroll
    for (int i = 0; i < 4; i++)
      bfr[i] = *(const s16x8*)(Lb + (wn*64 + i*16 + lr)*128 + (((4 + lk) ^ swl) * 16));
    __builtin_amdgcn_s_barrier();
    asm volatile("s_waitcnt lgkmcnt(0)" ::: "memory");
    __builtin_amdgcn_s_setprio(1);
#pragma unroll
    for (int mi = 0; mi < 4; mi++)
#pragma unroll
      for (int ni = 0; ni < 4; ni++)
        acc[mi][ni] = __builtin_amdgcn_mfma_f32_16x16x32_bf16(afr[mi], bfr[ni], acc[mi][ni], 0, 0, 0);
    __builtin_amdgcn_s_setprio(0);
    __builtin_amdgcn_s_barrier();

    // ---- phase 4 ----
#pragma unroll
    for (int i = 0; i < 4; i++)
      afr[i] = *(const s16x8*)(La + (wm*128 + 64 + i*16 + lr)*128 + (((4 + lk) ^ swl) * 16));
    __builtin_amdgcn_s_barrier();
    asm volatile("s_waitcnt lgkmcnt(0)" ::: "memory");
    __builtin_amdgcn_s_setprio(1);
#pragma unroll
    for (int mi = 0; mi < 4; mi++)
#pragma unroll
      for (int ni = 0; ni < 4; ni++)
        acc[4+mi][ni] = __builtin_amdgcn_mfma_f32_16x16x32_bf16(afr[mi], bfr[ni], acc[4+mi][ni], 0, 0, 0);
    __builtin_amdgcn_s_setprio(0);
    asm volatile("s_waitcnt vmcnt(0)" ::: "memory");
    __builtin_amdgcn_s_barrier();
  }

#pragma unroll
  for (int mi = 0; mi < 8; mi++){
#pragma unroll
    for (int ni = 0; ni < 4; ni++){
      const int row = m0 + wm*128 + mi*16 + lk*4;
      const int col = n0 + wn*64 + ni*16 + lr;
      const float bv = bias[col];
      if (VT && col >= vstart){
        const int vh = (col - vstart) >> 6, vd = (col - vstart) & 63;
        const int bb = row >> 11, ss = row & 2047;
        s16x4 o4;
#pragma unroll
        for (int i = 0; i < 4; i++) o4[i] = (short)f2bn(acc[mi][ni][i] + bv);
        *(s16x4*)(vt + ((size_t)((bb*16 + vh)*64 + vd))*2048 + ss) = o4;
      } else {
#pragma unroll
        for (int i = 0; i < 4; i++){
          float v = acc[mi][ni][i] + bv;
          if (MODE == 2) v = fmaxf(v, 0.f);
          if (MODE == 0 && col < scaleLim) v *= scale;
          Cb[(size_t)(row + i) * N + col] = f2bn(v);
        }
      }
    }
  }
}

// ---------------- flash attention: 8 waves, QBLK=128, KVBLK=64 ----------------
// Q pre-scaled by 0.125*log2(e); m=0 softmax (exp2 direct).
// Row-sum via matrix pipe: lsum = mfma(P_frag, ONES) -> zero cross-lane reduction.
// CAUSAL: grid (32, 8): q-tiles {15-y, y}. cross: grid (32, 16).
template<bool CAUSAL>
__global__ void __launch_bounds__(512) k_attn(const ushort* __restrict__ Q, const ushort* __restrict__ Kg,
    const ushort* __restrict__ Vt, ushort* __restrict__ O, int sQ, int sK, int SQ, int SKV)
{
  __shared__ __align__(16) ushort Kl[2][64*64];
  __shared__ __align__(16) ushort Vl[2][64*64];
  __shared__ __align__(16) ushort Pl[8][16*64];
  const int t = threadIdx.x, w = t >> 6, u = t & 63, lr = u & 15, lk = u >> 4;
  const int hb = blockIdx.x;
  const int b = hb >> 4, h = hb & 15;
  const int srow = t >> 3, scol = t & 7;
  const size_t kvbase = (size_t)b * SKV;
  const size_t vtbase = (size_t)((b*16 + h)*64);
  char* Pc = (char*)&Pl[w][0];
  const int swzq = (lr & 7) << 4;

  s16x8 ONES;
#pragma unroll
  for (int j = 0; j < 8; j++) ONES[j] = (short)0x3F80;   // bf16 1.0

  auto stage = [&](int kt, int buf){
    gload16(Kg + (kvbase + kt*64 + srow)*sK + h*64 + 8*(scol ^ (srow & 7)), &Kl[buf][0] + w*512);
    gload16(Vt + (vtbase + srow)*SKV + kt*64 + 8*(scol ^ (srow & 7)), &Vl[buf][0] + w*512);
  };

  const int NREP = CAUSAL ? 2 : 1;
#pragma unroll 1
  for (int rep = 0; rep < NREP; rep++){
    const int qt = CAUSAL ? (rep ? (int)blockIdx.y : (int)(2*gridDim.y - 1 - blockIdx.y))
                          : (int)blockIdx.y;
    const int q0 = qt * 128;

    const ushort* qp = Q + (size_t)(b*SQ + q0 + w*16 + lr) * sQ + h*64 + lk*8;
    s16x8 qf0 = *(const s16x8*)qp;
    s16x8 qf1 = *(const s16x8*)(qp + 32);

    f32x4 oacc[4] = {};
    f32x4 lsum = {};
    const int nkt = CAUSAL ? (2*qt + 2) : (SKV >> 6);

    stage(0, 0);
    __syncthreads();

    for (int kt = 0; kt < nkt; kt++){
      const int buf = kt & 1;
      if (kt + 1 < nkt) stage(kt + 1, buf ^ 1);
      char* Kc = (char*)&Kl[buf][0];
      char* Vc = (char*)&Vl[buf][0];

      // S^T = K @ Q : lane holds S[q=lr][key = 16ni + 4lk + i] (already *0.125*log2e)
      f32x4 sacc[4] = {};
      __builtin_amdgcn_s_setprio(1);
#pragma unroll
      for (int ks = 0; ks < 2; ks++){
        s16x8 qf = ks ? qf1 : qf0;
#pragma unroll
        for (int ni = 0; ni < 4; ni++){
          int key = ni*16 + lr;
          s16x8 kf = *(const s16x8*)(Kc + key*128 + ((ks*64 + lk*16) ^ ((key & 7) << 4)));
          sacc[ni] = __builtin_amdgcn_mfma_f32_16x16x32_bf16(kf, qf, sacc[ni], 0, 0, 0);
        }
      }
      __builtin_amdgcn_s_setprio(0);
      if (CAUSAL && kt >= 2*qt){
        const int koff = kt*64 - q0;
#pragma unroll
        for (int ni = 0; ni < 4; ni++)
#pragma unroll
          for (int i = 0; i < 4; i++)
            if (koff + 16*ni + lk*4 + i > w*16 + lr) sacc[ni][i] = -1e30f;
      }

#pragma unroll
      for (int ni = 0; ni < 4; ni++)
#pragma unroll
        for (int i = 0; i < 4; i++) sacc[ni][i] = __builtin_exp2f(sacc[ni][i]);

#pragma unroll
      for (int ni = 0; ni < 4; ni++){
        s16x4 pk;
#pragma unroll
        for (int i = 0; i < 4; i++) pk[i] = (short)f2bn(sacc[ni][i]);
        *(s16x4*)(Pc + lr*128 + ((32*ni + 8*lk) ^ swzq)) = pk;
      }

      __builtin_amdgcn_s_setprio(1);
#pragma unroll
      for (int ks = 0; ks < 2; ks++){
        s16x8 pf = *(const s16x8*)(Pc + lr*128 + ((ks*64 + lk*16) ^ swzq));
        lsum = __builtin_amdgcn_mfma_f32_16x16x32_bf16(pf, ONES, lsum, 0, 0, 0);
#pragma unroll
        for (int ni = 0; ni < 4; ni++){
          int d = ni*16 + lr;
          s16x8 vf = *(const s16x8*)(Vc + d*128 + ((ks*64 + lk*16) ^ ((d & 7) << 4)));
          oacc[ni] = __builtin_amdgcn_mfma_f32_16x16x32_bf16(pf, vf, oacc[ni], 0, 0, 0);
        }
      }
      __builtin_amdgcn_s_setprio(0);
      __syncthreads();
    }

    // lsum[i] holds the denominator for row q = q0 + w*16 + lk*4 + i
    float invl[4];
#pragma unroll
    for (int i = 0; i < 4; i++) invl[i] = 1.f / lsum[i];
#pragma unroll
    for (int ni = 0; ni < 4; ni++)
#pragma unroll
      for (int i = 0; i < 4; i++)
        O[(size_t)(b*SQ + q0 + w*16 + lk*4 + i)*1024 + h*64 + ni*16 + lr] = f2bn(oacc[ni][i] * invl[i]);
  }
}

// ---------------- residual + LayerNorm (E=1024), optional second partial ----------------
template<bool WB16>
__global__ void __launch_bounds__(256) k_ln(const float* __restrict__ R, const float* __restrict__ P,
    const float* __restrict__ P2, const float* __restrict__ G, const float* __restrict__ Bv,
    float* __restrict__ Of, ushort* __restrict__ Ob)
{
  const int row = blockIdx.x, t = threadIdx.x, w = t >> 6, u = t & 63;
  const size_t base = (size_t)row * 1024 + t * 4;
  f32x4 r = *(const f32x4*)(R + base);
  f32x4 p = *(const f32x4*)(P + base);
  f32x4 v = r + p;
  if (P2){ f32x4 p2 = *(const f32x4*)(P2 + base); v += p2; }
  float s = 0.f, q = 0.f;
#pragma unroll
  for (int j = 0; j < 4; j++){ s += v[j]; q += v[j]*v[j]; }
#pragma unroll
  for (int md = 1; md < 64; md <<= 1){ s += __shfl_xor(s, md); q += __shfl_xor(q, md); }
  __shared__ float ps[4], pq[4];
  if (u == 0){ ps[w] = s; pq[w] = q; }
  __syncthreads();
  s = ps[0] + ps[1] + ps[2] + ps[3];
  q = pq[0] + pq[1] + pq[2] + pq[3];
  const float mean = s * (1.f/1024.f);
  const float var  = q * (1.f/1024.f) - mean*mean;
  const float rstd = rsqrtf(var + 1e-5f);
  f32x4 g4 = *(const f32x4*)(G  + t*4);
  f32x4 b4 = *(const f32x4*)(Bv + t*4);
  f32x4 o;
#pragma unroll
  for (int j = 0; j < 4; j++) o[j] = (v[j] - mean) * rstd * g4[j] + b4[j];
  *(f32x4*)(Of + base) = o;
  if (WB16){
    s16x4 ob;
#pragma unroll
    for (int j = 0; j < 4; j++) ob[j] = (short)f2bn(o[j]);
    *(s16x4*)(Ob + base) = ob;
  }
}

// ---------------- launch ----------------
extern "C" void kernel_launch(void* const* d_in, const int* in_sizes, int n_in,
                              void* d_out, int out_size, void* d_ws, size_t ws_size,
                              hipStream_t stream)
{
  const float* x   = (const float*)d_in[0];
  const float* enc = (const float*)d_in[1];
  const float* aw[8]; const float* ab[8];
  for (int i = 0; i < 8; i++){ aw[i] = (const float*)d_in[2 + 2*i]; ab[i] = (const float*)d_in[3 + 2*i]; }
  const float* w1 = (const float*)d_in[18]; const float* b1 = (const float*)d_in[19];
  const float* w2 = (const float*)d_in[20]; const float* b2 = (const float*)d_in[21];
  const float* lg[3] = {(const float*)d_in[22], (const float*)d_in[24], (const float*)d_in[26]};
  const float* lb[3] = {(const float*)d_in[23], (const float*)d_in[25], (const float*)d_in[27]};
  float* out = (float*)d_out;

  const size_t MB = 1024ull * 1024ull;
  if (ws_size < 129 * MB) return;
  char* ws = (char*)d_ws;
  ushort* wqkv = (ushort*)(ws + 0*MB);
  ushort* wcq  = (ushort*)(ws + 6*MB);
  ushort* wkv  = (ushort*)(ws + 8*MB);
  ushort* wo1w = (ushort*)(ws + 12*MB);
  ushort* wo2w = (ushort*)(ws + 14*MB);
  ushort* w1b  = (ushort*)(ws + 16*MB);
  ushort* w2b  = (ushort*)(ws + 24*MB);
  ushort* xb   = (ushort*)(ws + 32*MB);     // dead after QKV
  ushort* encb = (ushort*)(ws + 40*MB);     // dead after cKV
  ushort* attb = (ushort*)(ws + 48*MB);
  float*  proj = (float*)(ws + 56*MB);
  float*  x1f  = (float*)(ws + 72*MB);
  ushort* xab  = (ushort*)(ws + 88*MB);
  // phase region [96MB,128MB)
  ushort* QKVb    = (ushort*)(ws + 96*MB);
  ushort* Vt1     = (ushort*)(ws + 120*MB);
  ushort* crossQb = (ushort*)(ws + 96*MB);
  ushort* encKVb  = (ushort*)(ws + 104*MB);
  ushort* Vt2     = (ushort*)(ws + 120*MB);
  ushort* hb      = (ushort*)(ws + 96*MB);   // FFN1 out (live through FFN2)
  float*  pWO     = (float*)(ws + 96*MB);    // wo split-K partial (phase region dead then)
  float*  pFF     = (float*)(ws + 32*MB);    // FFN2 partial (xb/encb dead)
  float*  bqkv = (float*)(ws + 128*MB);
  float*  bkv  = (float*)(ws + 128*MB + 16384);

  const long long ssWO  = ((long long)(96 - 56) * (long long)MB) / 4;
  const long long ssFFN = ((long long)(32 - 56) * (long long)MB) / 4;   // negative offset

  // ---- fused conversions ----
  ConvArgs ca;
  const float* srcs[17] = { x, enc, aw[0], aw[1], aw[2], aw[3], aw[4], aw[5], aw[6], aw[7],
                            w1, w2, ab[0], ab[1], ab[2], ab[5], ab[6] };
  void* dsts[17] = { xb, encb, wqkv, wqkv + 1048576, wqkv + 2097152, wo1w, wcq, wkv, wkv + 1048576, wo2w,
                     w1b, w2b, bqkv, bqkv + 1024, bqkv + 2048, bkv, bkv + 1024 };
  int nels[17] = { 4194304, 4194304, 1048576, 1048576, 1048576, 1048576, 1048576, 1048576, 1048576, 1048576,
                   4194304, 4194304, 1024, 1024, 1024, 1024, 1024 };
  int acc_blk = 0;
  for (int i = 0; i < 17; i++){
    ca.src[i] = srcs[i]; ca.dst[i] = dsts[i]; ca.nel[i] = nels[i];
    acc_blk += (nels[i] + 2047) / 2048;
    ca.blk_end[i] = acc_blk;
  }
  ca.f32mask = 0x1F000u;
  k_conv<<<acc_blk, 256, 0, stream>>>(ca);

  // ---- self-attention block ----
  // QKV: Q cols scaled, V cols (>=2048) written transposed straight into Vt1
  k_gemm256<0,true><<<dim3(12,16), 512, 0, stream>>>(xb, wqkv, bqkv, QKVb, 3072, 1024, 1024, 1024,
                                                     1024, SCALE_C, Vt1, 2048);
  k_attn<true><<<dim3(32,8), 512, 0, stream>>>(QKVb, QKVb + 1024, Vt1, attb, 3072, 3072, 2048, 2048);
  k_gemmS<<<dim3(8,32,2), 256, 0, stream>>>(attb, wo1w, ab[3], proj, 4096, 1024, 512, 1024, 1024, ssWO);
  k_ln<true><<<4096, 256, 0, stream>>>(x, proj, pWO, lg[0], lb[0], x1f, xab);

  // ---- cross-attention block: fused cQ + cKV (768 blocks, XCD-aware tiling) ----
  k_gemmB<<<768, 256, 0, stream>>>(xab, wcq, ab[4], crossQb, encb, wkv, bkv, encKVb, Vt2, SCALE_C);
  k_attn<false><<<dim3(32,16), 512, 0, stream>>>(crossQb, encKVb, Vt2, attb, 1024, 2048, 2048, 2048);
  k_gemmS<<<dim3(8,32,2), 256, 0, stream>>>(attb, wo2w, ab[7], proj, 4096, 1024, 512, 1024, 1024, ssWO);
  k_ln<true><<<4096, 256, 0, stream>>>(x1f, proj, pWO, lg[1], lb[1], x1f, xab);   // x1f -> x2 in place

  // ---- FFN block ----
  k_gemm256<2,false><<<dim3(16,16), 512, 0, stream>>>(xab, w1b, b1, hb, 4096, 1024, 1024, 1024,
                                                      0, 1.f, nullptr, 1 << 30);
  k_gemmS<<<dim3(8,32,2), 256, 0, stream>>>(hb, w2b, b2, proj, 4096, 1024, 2048, 4096, 4096, ssFFN);
  k_ln<false><<<4096, 256, 0, stream>>>(x1f, proj, pFF, lg[2], lb[2], out, nullptr);
}

// Round 17
// 362.747 us; speedup vs baseline: 1.1534x; 1.0567x over previous
//
#include <hip/hip_runtime.h>
#include <hip/hip_bf16.h>
#include <stdint.h>

typedef __attribute__((ext_vector_type(8)))  short s16x8;
typedef __attribute__((ext_vector_type(4)))  short s16x4;
typedef __attribute__((ext_vector_type(4)))  float f32x4;

#define DEV static __device__ __forceinline__

DEV ushort f2bu(float f){
  unsigned u = __builtin_bit_cast(unsigned, f);
  return (ushort)((u + 0x7fffu + ((u >> 16) & 1u)) >> 16);   // RNE f32->bf16
}
DEV ushort f2bn(float f){
  return __builtin_bit_cast(ushort, __float2bfloat16(f));
}

DEV void gload16(const void* g, void* l){
  __builtin_amdgcn_global_load_lds((const __attribute__((address_space(1))) void*)g,
                                   (__attribute__((address_space(3))) void*)l, 16, 0, 0);
}

#define SCALE_C 0.18033688f   // 0.125 * log2(e), folded into Q projections

// ---------------- fused f32->bf16 conversions + f32 bias concat ----------------
struct ConvArgs {
  const float* src[17];
  void*        dst[17];
  int blk_end[17];
  int nel[17];
  unsigned f32mask;
};

__global__ void __launch_bounds__(256) k_conv(ConvArgs a){
  int bi = blockIdx.x, seg = 0;
  while (bi >= a.blk_end[seg]) seg++;
  int b0 = seg ? a.blk_end[seg-1] : 0;
  long off = (long)(bi - b0)*2048 + (long)threadIdx.x*8;
  if (off >= a.nel[seg]) return;
  const float* s = a.src[seg] + off;
  f32x4 v0 = *(const f32x4*)s;
  f32x4 v1 = *(const f32x4*)(s+4);
  if ((a.f32mask >> seg) & 1u){
    float* d = (float*)a.dst[seg] + off;
    *(f32x4*)d = v0; *(f32x4*)(d+4) = v1;
  } else {
    ushort* d = (ushort*)a.dst[seg] + off;
    s16x8 o;
#pragma unroll
    for (int j = 0; j < 4; j++){ o[j] = (short)f2bu(v0[j]); o[4+j] = (short)f2bu(v1[j]); }
    *(s16x8*)d = o;
  }
}

// ---------------- 128x128 dbuf GEMM, split-K f32 out (wo1/wo2/FFN2), XCD-swizzled ----------------
__global__ void __launch_bounds__(256) k_gemmS(const ushort* __restrict__ A, const ushort* __restrict__ W,
    const float* __restrict__ bias, float* __restrict__ Cf,
    int M, int N, int Kext, int lda, int ldb, long long sstride)
{
  __shared__ __align__(16) ushort lsA[2][128*64];
  __shared__ __align__(16) ushort lsB[2][128*64];
  const int t = threadIdx.x, w = t >> 6, u = t & 63, lr = u & 15, lk = u >> 4;
  const int gx = gridDim.x, nwg = gx * gridDim.y;
  const int id = blockIdx.y * gx + blockIdx.x;
  const int swz = (id & 7) * (nwg >> 3) + (id >> 3);     // bijective: nwg % 8 == 0
  const int n0 = (swz % gx) * 128, m0 = (swz / gx) * 128;
  const int s = blockIdx.z;
  const int wm = w >> 1, wn = w & 1;
  const int rA = t >> 3, c8 = (t & 7) * 8;
  const ushort* Ap = A + (size_t)(m0 + rA) * lda + (size_t)s * Kext + c8;
  const ushort* Wp = W + (size_t)(n0 + rA) * ldb + (size_t)s * Kext + c8;
  if (s){ bias = nullptr; Cf += sstride; }
  f32x4 acc[4][4] = {};
  const int nk = Kext >> 6;

  auto stage = [&](int k0, int buf){
#pragma unroll
    for (int j = 0; j < 4; j++){
      gload16(Ap + (size_t)j*32*lda + k0, &lsA[buf][0] + j*2048 + w*512);
      gload16(Wp + (size_t)j*32*ldb + k0, &lsB[buf][0] + j*2048 + w*512);
    }
  };
  stage(0, 0);
  for (int tk = 0; tk < nk; ++tk){
    __syncthreads();
    if (tk + 1 < nk) stage((tk + 1) << 6, (tk + 1) & 1);
    const ushort* La = &lsA[tk & 1][0];
    const ushort* Lb = &lsB[tk & 1][0];
#pragma unroll
    for (int ks = 0; ks < 2; ks++){
      s16x8 af[4], bfr[4];
#pragma unroll
      for (int i = 0; i < 4; i++) af[i]  = *(const s16x8*)(La + (wm*64 + i*16 + lr)*64 + ks*32 + lk*8);
#pragma unroll
      for (int i = 0; i < 4; i++) bfr[i] = *(const s16x8*)(Lb + (wn*64 + i*16 + lr)*64 + ks*32 + lk*8);
#pragma unroll
      for (int mi = 0; mi < 4; mi++)
#pragma unroll
        for (int ni = 0; ni < 4; ni++)
          acc[mi][ni] = __builtin_amdgcn_mfma_f32_16x16x32_bf16(af[mi], bfr[ni], acc[mi][ni], 0, 0, 0);
    }
  }

#pragma unroll
  for (int mi = 0; mi < 4; mi++){
#pragma unroll
    for (int ni = 0; ni < 4; ni++){
      const int row = m0 + wm*64 + mi*16 + lk*4;
      const int col = n0 + wn*64 + ni*16 + lr;
      const float bv = bias ? bias[col] : 0.f;
#pragma unroll
      for (int i = 0; i < 4; i++)
        Cf[(size_t)(row + i) * N + col] = acc[mi][ni][i] + bv;
    }
  }
}

// ================= 256x256 8-phase GEMM body (shared by k_gemm256 / k_gemmX) =================
#define G256_BODY(Ap, Wp, lda, ldb, nt)                                                          \
  f32x4 acc[8][4] = {};                                                                          \
  const int swl = lr & 7;                                                                        \
  s16x8 afr[4], bfr[4];                                                                          \
  _Pragma("unroll")                                                                              \
  for (int j = 0; j < 4; j++){                                                                   \
    gload16(Ap + (size_t)(64*j)*lda, &lsA[0][0] + w*512 + j*4096);                               \
    gload16(Wp + (size_t)(64*j)*ldb, &lsB[0][0] + w*512 + j*4096);                               \
  }                                                                                              \
  asm volatile("s_waitcnt vmcnt(0)" ::: "memory");                                               \
  __builtin_amdgcn_s_barrier();                                                                  \
  for (int tk = 0; tk < nt; ++tk){                                                               \
    const char* La = (const char*)&lsA[tk & 1][0];                                               \
    const char* Lb = (const char*)&lsB[tk & 1][0];                                               \
    ushort* dA = &lsA[(tk & 1) ^ 1][0] + w*512;                                                  \
    ushort* dB = &lsB[(tk & 1) ^ 1][0] + w*512;                                                  \
    const bool pf = (tk + 1 < nt);                                                               \
    const size_t k1 = (size_t)(tk + 1) << 6;                                                     \
    _Pragma("unroll")                                                                            \
    for (int i = 0; i < 4; i++)                                                                  \
      afr[i] = *(const s16x8*)(La + (wm*128 + i*16 + lr)*128 + ((lk ^ swl) * 16));               \
    _Pragma("unroll")                                                                            \
    for (int i = 0; i < 4; i++)                                                                  \
      bfr[i] = *(const s16x8*)(Lb + (wn*64 + i*16 + lr)*128 + ((lk ^ swl) * 16));                \
    if (pf){                                                                                     \
      gload16(Ap + k1, dA);                                                                      \
      gload16(Wp + k1, dB);                                                                      \
      gload16(Ap + (size_t)64*lda + k1, dA + 4096);                                              \
      gload16(Wp + (size_t)64*ldb + k1, dB + 4096);                                              \
    }                                                                                            \
    __builtin_amdgcn_s_barrier();                                                                \
    asm volatile("s_waitcnt lgkmcnt(0)" ::: "memory");                                           \
    __builtin_amdgcn_s_setprio(1);                                                               \
    _Pragma("unroll")                                                                            \
    for (int mi = 0; mi < 4; mi++)                                                               \
      _Pragma("unroll")                                                                          \
      for (int ni = 0; ni < 4; ni++)                                                             \
        acc[mi][ni] = __builtin_amdgcn_mfma_f32_16x16x32_bf16(afr[mi], bfr[ni], acc[mi][ni], 0, 0, 0); \
    __builtin_amdgcn_s_setprio(0);                                                               \
    __builtin_amdgcn_s_barrier();                                                                \
    _Pragma("unroll")                                                                            \
    for (int i = 0; i < 4; i++)                                                                  \
      afr[i] = *(const s16x8*)(La + (wm*128 + 64 + i*16 + lr)*128 + ((lk ^ swl) * 16));          \
    if (pf){                                                                                     \
      gload16(Ap + (size_t)128*lda + k1, dA + 8192);                                             \
      gload16(Wp + (size_t)128*ldb + k1, dB + 8192);                                             \
      gload16(Ap + (size_t)192*lda + k1, dA + 12288);                                            \
      gload16(Wp + (size_t)192*ldb + k1, dB + 12288);                                            \
    }                                                                                            \
    __builtin_amdgcn_s_barrier();                                                                \
    asm volatile("s_waitcnt lgkmcnt(0)" ::: "memory");                                           \
    __builtin_amdgcn_s_setprio(1);                                                               \
    _Pragma("unroll")                                                                            \
    for (int mi = 0; mi < 4; mi++)                                                               \
      _Pragma("unroll")                                                                          \
      for (int ni = 0; ni < 4; ni++)                                                             \
        acc[4+mi][ni] = __builtin_amdgcn_mfma_f32_16x16x32_bf16(afr[mi], bfr[ni], acc[4+mi][ni], 0, 0, 0); \
    __builtin_amdgcn_s_setprio(0);                                                               \
    __builtin_amdgcn_s_barrier();                                                                \
    _Pragma("unroll")                                                                            \
    for (int i = 0; i < 4; i++)                                                                  \
      afr[i] = *(const s16x8*)(La + (wm*128 + i*16 + lr)*128 + (((4 + lk) ^ swl) * 16));         \
    _Pragma("unroll")                                                                            \
    for (int i = 0; i < 4; i++)                                                                  \
      bfr[i] = *(const s16x8*)(Lb + (wn*64 + i*16 + lr)*128 + (((4 + lk) ^ swl) * 16));          \
    __builtin_amdgcn_s_barrier();                                                                \
    asm volatile("s_waitcnt lgkmcnt(0)" ::: "memory");                                           \
    __builtin_amdgcn_s_setprio(1);                                                               \
    _Pragma("unroll")                                                                            \
    for (int mi = 0; mi < 4; mi++)                                                               \
      _Pragma("unroll")                                                                          \
      for (int ni = 0; ni < 4; ni++)                                                             \
        acc[mi][ni] = __builtin_amdgcn_mfma_f32_16x16x32_bf16(afr[mi], bfr[ni], acc[mi][ni], 0, 0, 0); \
    __builtin_amdgcn_s_setprio(0);                                                               \
    __builtin_amdgcn_s_barrier();                                                                \
    _Pragma("unroll")                                                                            \
    for (int i = 0; i < 4; i++)                                                                  \
      afr[i] = *(const s16x8*)(La + (wm*128 + 64 + i*16 + lr)*128 + (((4 + lk) ^ swl) * 16));    \
    __builtin_amdgcn_s_barrier();                                                                \
    asm volatile("s_waitcnt lgkmcnt(0)" ::: "memory");                                           \
    __builtin_amdgcn_s_setprio(1);                                                               \
    _Pragma("unroll")                                                                            \
    for (int mi = 0; mi < 4; mi++)                                                               \
      _Pragma("unroll")                                                                          \
      for (int ni = 0; ni < 4; ni++)                                                             \
        acc[4+mi][ni] = __builtin_amdgcn_mfma_f32_16x16x32_bf16(afr[mi], bfr[ni], acc[4+mi][ni], 0, 0, 0); \
    __builtin_amdgcn_s_setprio(0);                                                               \
    asm volatile("s_waitcnt vmcnt(0)" ::: "memory");                                             \
    __builtin_amdgcn_s_barrier();                                                                \
  }

// ---------------- 256x256 8-phase GEMM: QKV / FFN1 ----------------
// MODE 0: bf16 out, cols<scaleLim scaled; MODE 2: relu + bf16 out.
// VT: cols >= vstart written transposed to vt[b][h][64][2048].
template<int MODE, bool VT>
__global__ void __launch_bounds__(512, 1) k_gemm256(const ushort* __restrict__ A, const ushort* __restrict__ W,
    const float* __restrict__ bias, ushort* __restrict__ Cb,
    int N, int Ktot, int lda, int ldb, int scaleLim, float scale,
    ushort* __restrict__ vt, int vstart)
{
  __shared__ __align__(16) ushort lsA[2][256*64];
  __shared__ __align__(16) ushort lsB[2][256*64];
  const int t = threadIdx.x, w = t >> 6, u = t & 63, lr = u & 15, lk = u >> 4;
  const int gx = gridDim.x;
  const int nwg = gx * gridDim.y;
  const int id = blockIdx.y * gx + blockIdx.x;
  const int swz = (id & 7) * (nwg >> 3) + (id >> 3);      // bijective: nwg % 8 == 0
  const int n0 = (swz % gx) * 256, m0 = (swz / gx) * 256;
  const int wm = w >> 2, wn = w & 3;
  const int nt = Ktot >> 6;

  const int r0 = w*8 + (u >> 3), cc = u & 7;
  const int csw = 8 * (cc ^ (r0 & 7));
  const ushort* Ap = A + (size_t)(m0 + r0) * lda + csw;
  const ushort* Wp = W + (size_t)(n0 + r0) * ldb + csw;

  G256_BODY(Ap, Wp, lda, ldb, nt)

#pragma unroll
  for (int mi = 0; mi < 8; mi++){
#pragma unroll
    for (int ni = 0; ni < 4; ni++){
      const int row = m0 + wm*128 + mi*16 + lk*4;
      const int col = n0 + wn*64 + ni*16 + lr;
      const float bv = bias[col];
      if (VT && col >= vstart){
        const int vh = (col - vstart) >> 6, vd = (col - vstart) & 63;
        const int bb = row >> 11, ss = row & 2047;
        s16x4 o4;
#pragma unroll
        for (int i = 0; i < 4; i++) o4[i] = (short)f2bn(acc[mi][ni][i] + bv);
        *(s16x4*)(vt + ((size_t)((bb*16 + vh)*64 + vd))*2048 + ss) = o4;
      } else {
#pragma unroll
        for (int i = 0; i < 4; i++){
          float v = acc[mi][ni][i] + bv;
          if (MODE == 2) v = fmaxf(v, 0.f);
          if (MODE == 0 && col < scaleLim) v *= scale;
          Cb[(size_t)(row + i) * N + col] = f2bn(v);
        }
      }
    }
  }
}

// ---------------- fused cQ + cKV via 256x256 8-phase engine (192 blocks) ----------------
// swz < 64:  cQ  C0[4096,1024] = A0 @ W0^T * scale0
// swz >= 64: cKV C1[4096,2048] = A1 @ W1^T; cols >= 1024 transposed into vt
__global__ void __launch_bounds__(512, 1) k_gemmX(
    const ushort* __restrict__ A0, const ushort* __restrict__ W0, const float* __restrict__ b0,
    ushort* __restrict__ C0,
    const ushort* __restrict__ A1, const ushort* __restrict__ W1, const float* __restrict__ b1,
    ushort* __restrict__ C1, ushort* __restrict__ vt, float scale0)
{
  __shared__ __align__(16) ushort lsA[2][256*64];
  __shared__ __align__(16) ushort lsB[2][256*64];
  const int t = threadIdx.x, w = t >> 6, u = t & 63, lr = u & 15, lk = u >> 4;
  const int id = blockIdx.x;                       // 0..191
  const int swz = (id & 7) * 24 + (id >> 3);       // bijective over 192
  const int wm = w >> 2, wn = w & 3;

  const ushort *A, *W; const float* bias; ushort* C;
  int N, m0, n0; bool seg1;
  if (swz < 64){
    A = A0; W = W0; bias = b0; C = C0; N = 1024; seg1 = false;
    n0 = (swz & 3) * 256; m0 = (swz >> 2) * 256;
  } else {
    const int s2 = swz - 64;
    A = A1; W = W1; bias = b1; C = C1; N = 2048; seg1 = true;
    n0 = (s2 & 7) * 256; m0 = (s2 >> 3) * 256;
  }

  const int r0 = w*8 + (u >> 3), cc = u & 7;
  const int csw = 8 * (cc ^ (r0 & 7));
  const ushort* Ap = A + (size_t)(m0 + r0) * 1024 + csw;
  const ushort* Wp = W + (size_t)(n0 + r0) * 1024 + csw;

  G256_BODY(Ap, Wp, 1024, 1024, 16)

#pragma unroll
  for (int mi = 0; mi < 8; mi++){
#pragma unroll
    for (int ni = 0; ni < 4; ni++){
      const int row = m0 + wm*128 + mi*16 + lk*4;
      const int col = n0 + wn*64 + ni*16 + lr;
      const float bv = bias[col];
      if (seg1 && col >= 1024){
        const int vh = (col - 1024) >> 6, vd = (col - 1024) & 63;
        const int bb = row >> 11, ss = row & 2047;
        s16x4 o4;
#pragma unroll
        for (int i = 0; i < 4; i++) o4[i] = (short)f2bn(acc[mi][ni][i] + bv);
        *(s16x4*)(vt + ((size_t)((bb*16 + vh)*64 + vd))*2048 + ss) = o4;
      } else {
#pragma unroll
        for (int i = 0; i < 4; i++){
          float v = acc[mi][ni][i] + bv;
          if (!seg1) v *= scale0;
          C[(size_t)(row + i) * N + col] = f2bn(v);
        }
      }
    }
  }
}

// ---------------- flash attention: 8 waves, QBLK=128, KVBLK=64 ----------------
// Q pre-scaled by 0.125*log2(e); m=0 softmax (exp2 direct).
// Row-sum via matrix pipe: lsum = mfma(P_frag, ONES) -> zero cross-lane reduction.
// CAUSAL: grid (32, 8): q-tiles {15-y, y}. cross: grid (32, 16).
template<bool CAUSAL>
__global__ void __launch_bounds__(512) k_attn(const ushort* __restrict__ Q, const ushort* __restrict__ Kg,
    const ushort* __restrict__ Vt, ushort* __restrict__ O, int sQ, int sK, int SQ, int SKV)
{
  __shared__ __align__(16) ushort Kl[2][64*64];
  __shared__ __align__(16) ushort Vl[2][64*64];
  __shared__ __align__(16) ushort Pl[8][16*64];
  const int t = threadIdx.x, w = t >> 6, u = t & 63, lr = u & 15, lk = u >> 4;
  const int hb = blockIdx.x;
  const int b = hb >> 4, h = hb & 15;
  const int srow = t >> 3, scol = t & 7;
  const size_t kvbase = (size_t)b * SKV;
  const size_t vtbase = (size_t)((b*16 + h)*64);
  char* Pc = (char*)&Pl[w][0];
  const int swzq = (lr & 7) << 4;

  s16x8 ONES;
#pragma unroll
  for (int j = 0; j < 8; j++) ONES[j] = (short)0x3F80;   // bf16 1.0

  auto stage = [&](int kt, int buf){
    gload16(Kg + (kvbase + kt*64 + srow)*sK + h*64 + 8*(scol ^ (srow & 7)), &Kl[buf][0] + w*512);
    gload16(Vt + (vtbase + srow)*SKV + kt*64 + 8*(scol ^ (srow & 7)), &Vl[buf][0] + w*512);
  };

  const int NREP = CAUSAL ? 2 : 1;
#pragma unroll 1
  for (int rep = 0; rep < NREP; rep++){
    const int qt = CAUSAL ? (rep ? (int)blockIdx.y : (int)(2*gridDim.y - 1 - blockIdx.y))
                          : (int)blockIdx.y;
    const int q0 = qt * 128;

    const ushort* qp = Q + (size_t)(b*SQ + q0 + w*16 + lr) * sQ + h*64 + lk*8;
    s16x8 qf0 = *(const s16x8*)qp;
    s16x8 qf1 = *(const s16x8*)(qp + 32);

    f32x4 oacc[4] = {};
    f32x4 lsum = {};
    const int nkt = CAUSAL ? (2*qt + 2) : (SKV >> 6);

    stage(0, 0);
    __syncthreads();

    for (int kt = 0; kt < nkt; kt++){
      const int buf = kt & 1;
      if (kt + 1 < nkt) stage(kt + 1, buf ^ 1);
      char* Kc = (char*)&Kl[buf][0];
      char* Vc = (char*)&Vl[buf][0];

      // S^T = K @ Q : lane holds S[q=lr][key = 16ni + 4lk + i] (already *0.125*log2e)
      f32x4 sacc[4] = {};
      __builtin_amdgcn_s_setprio(1);
#pragma unroll
      for (int ks = 0; ks < 2; ks++){
        s16x8 qf = ks ? qf1 : qf0;
#pragma unroll
        for (int ni = 0; ni < 4; ni++){
          int key = ni*16 + lr;
          s16x8 kf = *(const s16x8*)(Kc + key*128 + ((ks*64 + lk*16) ^ ((key & 7) << 4)));
          sacc[ni] = __builtin_amdgcn_mfma_f32_16x16x32_bf16(kf, qf, sacc[ni], 0, 0, 0);
        }
      }
      __builtin_amdgcn_s_setprio(0);
      if (CAUSAL && kt >= 2*qt){
        const int koff = kt*64 - q0;
#pragma unroll
        for (int ni = 0; ni < 4; ni++)
#pragma unroll
          for (int i = 0; i < 4; i++)
            if (koff + 16*ni + lk*4 + i > w*16 + lr) sacc[ni][i] = -1e30f;
      }

#pragma unroll
      for (int ni = 0; ni < 4; ni++)
#pragma unroll
        for (int i = 0; i < 4; i++) sacc[ni][i] = __builtin_exp2f(sacc[ni][i]);

#pragma unroll
      for (int ni = 0; ni < 4; ni++){
        s16x4 pk;
#pragma unroll
        for (int i = 0; i < 4; i++) pk[i] = (short)f2bn(sacc[ni][i]);
        *(s16x4*)(Pc + lr*128 + ((32*ni + 8*lk) ^ swzq)) = pk;
      }

      __builtin_amdgcn_s_setprio(1);
#pragma unroll
      for (int ks = 0; ks < 2; ks++){
        s16x8 pf = *(const s16x8*)(Pc + lr*128 + ((ks*64 + lk*16) ^ swzq));
        lsum = __builtin_amdgcn_mfma_f32_16x16x32_bf16(pf, ONES, lsum, 0, 0, 0);
#pragma unroll
        for (int ni = 0; ni < 4; ni++){
          int d = ni*16 + lr;
          s16x8 vf = *(const s16x8*)(Vc + d*128 + ((ks*64 + lk*16) ^ ((d & 7) << 4)));
          oacc[ni] = __builtin_amdgcn_mfma_f32_16x16x32_bf16(pf, vf, oacc[ni], 0, 0, 0);
        }
      }
      __builtin_amdgcn_s_setprio(0);
      __syncthreads();
    }

    // lsum[i] holds the denominator for row q = q0 + w*16 + lk*4 + i
    float invl[4];
#pragma unroll
    for (int i = 0; i < 4; i++) invl[i] = 1.f / lsum[i];
#pragma unroll
    for (int ni = 0; ni < 4; ni++)
#pragma unroll
      for (int i = 0; i < 4; i++)
        O[(size_t)(b*SQ + q0 + w*16 + lk*4 + i)*1024 + h*64 + ni*16 + lr] = f2bn(oacc[ni][i] * invl[i]);
  }
}

// ---------------- residual + LayerNorm (E=1024), optional second partial ----------------
template<bool WB16>
__global__ void __launch_bounds__(256) k_ln(const float* __restrict__ R, const float* __restrict__ P,
    const float* __restrict__ P2, const float* __restrict__ G, const float* __restrict__ Bv,
    float* __restrict__ Of, ushort* __restrict__ Ob)
{
  const int row = blockIdx.x, t = threadIdx.x, w = t >> 6, u = t & 63;
  const size_t base = (size_t)row * 1024 + t * 4;
  f32x4 r = *(const f32x4*)(R + base);
  f32x4 p = *(const f32x4*)(P + base);
  f32x4 v = r + p;
  if (P2){ f32x4 p2 = *(const f32x4*)(P2 + base); v += p2; }
  float s = 0.f, q = 0.f;
#pragma unroll
  for (int j = 0; j < 4; j++){ s += v[j]; q += v[j]*v[j]; }
#pragma unroll
  for (int md = 1; md < 64; md <<= 1){ s += __shfl_xor(s, md); q += __shfl_xor(q, md); }
  __shared__ float ps[4], pq[4];
  if (u == 0){ ps[w] = s; pq[w] = q; }
  __syncthreads();
  s = ps[0] + ps[1] + ps[2] + ps[3];
  q = pq[0] + pq[1] + pq[2] + pq[3];
  const float mean = s * (1.f/1024.f);
  const float var  = q * (1.f/1024.f) - mean*mean;
  const float rstd = rsqrtf(var + 1e-5f);
  f32x4 g4 = *(const f32x4*)(G  + t*4);
  f32x4 b4 = *(const f32x4*)(Bv + t*4);
  f32x4 o;
#pragma unroll
  for (int j = 0; j < 4; j++) o[j] = (v[j] - mean) * rstd * g4[j] + b4[j];
  *(f32x4*)(Of + base) = o;
  if (WB16){
    s16x4 ob;
#pragma unroll
    for (int j = 0; j < 4; j++) ob[j] = (short)f2bn(o[j]);
    *(s16x4*)(Ob + base) = ob;
  }
}

// ---------------- launch ----------------
extern "C" void kernel_launch(void* const* d_in, const int* in_sizes, int n_in,
                              void* d_out, int out_size, void* d_ws, size_t ws_size,
                              hipStream_t stream)
{
  const float* x   = (const float*)d_in[0];
  const float* enc = (const float*)d_in[1];
  const float* aw[8]; const float* ab[8];
  for (int i = 0; i < 8; i++){ aw[i] = (const float*)d_in[2 + 2*i]; ab[i] = (const float*)d_in[3 + 2*i]; }
  const float* w1 = (const float*)d_in[18]; const float* b1 = (const float*)d_in[19];
  const float* w2 = (const float*)d_in[20]; const float* b2 = (const float*)d_in[21];
  const float* lg[3] = {(const float*)d_in[22], (const float*)d_in[24], (const float*)d_in[26]};
  const float* lb[3] = {(const float*)d_in[23], (const float*)d_in[25], (const float*)d_in[27]};
  float* out = (float*)d_out;

  const size_t MB = 1024ull * 1024ull;
  if (ws_size < 129 * MB) return;
  char* ws = (char*)d_ws;
  ushort* wqkv = (ushort*)(ws + 0*MB);
  ushort* wcq  = (ushort*)(ws + 6*MB);
  ushort* wkv  = (ushort*)(ws + 8*MB);
  ushort* wo1w = (ushort*)(ws + 12*MB);
  ushort* wo2w = (ushort*)(ws + 14*MB);
  ushort* w1b  = (ushort*)(ws + 16*MB);
  ushort* w2b  = (ushort*)(ws + 24*MB);
  ushort* xb   = (ushort*)(ws + 32*MB);     // dead after QKV
  ushort* encb = (ushort*)(ws + 40*MB);     // dead after cKV
  ushort* attb = (ushort*)(ws + 48*MB);
  float*  proj = (float*)(ws + 56*MB);
  float*  x1f  = (float*)(ws + 72*MB);
  ushort* xab  = (ushort*)(ws + 88*MB);
  // phase region [96MB,128MB)
  ushort* QKVb    = (ushort*)(ws + 96*MB);
  ushort* Vt1     = (ushort*)(ws + 120*MB);
  ushort* crossQb = (ushort*)(ws + 96*MB);
  ushort* encKVb  = (ushort*)(ws + 104*MB);
  ushort* Vt2     = (ushort*)(ws + 120*MB);
  ushort* hb      = (ushort*)(ws + 96*MB);   // FFN1 out (live through FFN2)
  float*  pWO     = (float*)(ws + 96*MB);    // wo split-K partial (phase region dead then)
  float*  pFF     = (float*)(ws + 32*MB);    // FFN2 partial (xb/encb dead)
  float*  bqkv = (float*)(ws + 128*MB);
  float*  bkv  = (float*)(ws + 128*MB + 16384);

  const long long ssWO  = ((long long)(96 - 56) * (long long)MB) / 4;
  const long long ssFFN = ((long long)(32 - 56) * (long long)MB) / 4;   // negative offset

  // ---- fused conversions ----
  ConvArgs ca;
  const float* srcs[17] = { x, enc, aw[0], aw[1], aw[2], aw[3], aw[4], aw[5], aw[6], aw[7],
                            w1, w2, ab[0], ab[1], ab[2], ab[5], ab[6] };
  void* dsts[17] = { xb, encb, wqkv, wqkv + 1048576, wqkv + 2097152, wo1w, wcq, wkv, wkv + 1048576, wo2w,
                     w1b, w2b, bqkv, bqkv + 1024, bqkv + 2048, bkv, bkv + 1024 };
  int nels[17] = { 4194304, 4194304, 1048576, 1048576, 1048576, 1048576, 1048576, 1048576, 1048576, 1048576,
                   4194304, 4194304, 1024, 1024, 1024, 1024, 1024 };
  int acc_blk = 0;
  for (int i = 0; i < 17; i++){
    ca.src[i] = srcs[i]; ca.dst[i] = dsts[i]; ca.nel[i] = nels[i];
    acc_blk += (nels[i] + 2047) / 2048;
    ca.blk_end[i] = acc_blk;
  }
  ca.f32mask = 0x1F000u;
  k_conv<<<acc_blk, 256, 0, stream>>>(ca);

  // ---- self-attention block ----
  // QKV: Q cols scaled, V cols (>=2048) written transposed straight into Vt1
  k_gemm256<0,true><<<dim3(12,16), 512, 0, stream>>>(xb, wqkv, bqkv, QKVb, 3072, 1024, 1024, 1024,
                                                     1024, SCALE_C, Vt1, 2048);
  k_attn<true><<<dim3(32,8), 512, 0, stream>>>(QKVb, QKVb + 1024, Vt1, attb, 3072, 3072, 2048, 2048);
  k_gemmS<<<dim3(8,32,2), 256, 0, stream>>>(attb, wo1w, ab[3], proj, 4096, 1024, 512, 1024, 1024, ssWO);
  k_ln<true><<<4096, 256, 0, stream>>>(x, proj, pWO, lg[0], lb[0], x1f, xab);

  // ---- cross-attention block: fused cQ + cKV via 256^2 8-phase engine (192 blocks) ----
  k_gemmX<<<192, 512, 0, stream>>>(xab, wcq, ab[4], crossQb, encb, wkv, bkv, encKVb, Vt2, SCALE_C);
  k_attn<false><<<dim3(32,16), 512, 0, stream>>>(crossQb, encKVb, Vt2, attb, 1024, 2048, 2048, 2048);
  k_gemmS<<<dim3(8,32,2), 256, 0, stream>>>(attb, wo2w, ab[7], proj, 4096, 1024, 512, 1024, 1024, ssWO);
  k_ln<true><<<4096, 256, 0, stream>>>(x1f, proj, pWO, lg[1], lb[1], x1f, xab);   // x1f -> x2 in place

  // ---- FFN block ----
  k_gemm256<2,false><<<dim3(16,16), 512, 0, stream>>>(xab, w1b, b1, hb, 4096, 1024, 1024, 1024,
                                                      0, 1.f, nullptr, 1 << 30);
  k_gemmS<<<dim3(8,32,2), 256, 0, stream>>>(hb, w2b, b2, proj, 4096, 1024, 2048, 4096, 4096, ssFFN);
  k_ln<false><<<4096, 256, 0, stream>>>(x1f, proj, pFF, lg[2], lb[2], out, nullptr);
}